// Round 11
// baseline (174.077 us; speedup 1.0000x reference)
//
#include <hip/hip_runtime.h>
#include <hip/hip_bf16.h>

#define NN 1024
#define DD 64
#define EE 16384
#define PP 8192
#define EPSF 1e-5f
#define SWP (DD + 8)   // padded LDS row stride in shorts (144 B)

typedef __hip_bfloat16 bf16;
typedef __attribute__((ext_vector_type(8))) short short8;
typedef __attribute__((ext_vector_type(4))) float f32x4;

static __device__ __forceinline__ float dec1(const void* src, int i, int fl) {
    if (fl) return ((const float*)src)[i];
    return __bfloat162float(((const bf16*)src)[i]);
}
static __device__ __forceinline__ unsigned short f2bf_u(float f) {
    bf16 h = __float2bfloat16(f);
    return *reinterpret_cast<unsigned short*>(&h);
}
static __device__ __forceinline__ float bfu2f(unsigned short u) {
    return __uint_as_float(((unsigned int)u) << 16);
}
static __device__ __forceinline__ int probe_fl(const void* emb) {
    int lane = threadIdx.x & 63;
    unsigned short raw = ((const unsigned short*)emb)[lane];
    float v = __uint_as_float(((unsigned int)raw) << 16);
    return (__ballot(!(fabsf(v) <= 1e3f)) != 0ull) ? 1 : 0;
}

// wave-level LayerNorm + write
static __device__ __forceinline__ void ln_write(float o, int node, int lane,
        float* __restrict__ hout, unsigned short* __restrict__ hbf) {
    float m = o;
    for (int off = 32; off; off >>= 1) m += __shfl_xor(m, off);
    m *= (1.f / DD);
    float d0 = o - m;
    float v = d0 * d0;
    for (int off = 32; off; off >>= 1) v += __shfl_xor(v, off);
    v *= (1.f / DD);
    float r = d0 * rsqrtf(v + EPSF);
    hout[node * DD + lane] = r;
    if (hbf) hbf[node * DD + lane] = f2bf_u(r);
}

// =============== K1: SAGE round 0 via edge-scan + eim/eimT slice build ===============
// blocks 0..255: node-group blocks (4 nodes each). Scan ALL edges (L2-resident 128KB):
//   - src in range  -> set bit in local eim slice (block-owned words, NO global atomics/zeroing)
//   - dst in range  -> deg++, local eimT slice, ballot-gather emb[x[src]] into sa
// blocks 256..322: decode WfT/hbw/gWf/linf to fp32 workspace for bstage/final.
__global__ __launch_bounds__(256) void k_sage0(
        const void* __restrict__ emb, const int* __restrict__ x, const int* __restrict__ ei,
        const void* __restrict__ sWl, const void* __restrict__ sbl, const void* __restrict__ sWr,
        const void* __restrict__ hW, const void* __restrict__ hb,
        const void* __restrict__ gW, const void* __restrict__ gb,
        const void* __restrict__ lW, const void* __restrict__ lb,
        float* __restrict__ h1,
        unsigned int* __restrict__ eim, unsigned int* __restrict__ eimT,
        float* __restrict__ WfT, float* __restrict__ hbw,
        float* __restrict__ gWf, float* __restrict__ linf) {
    const int b = blockIdx.x, tid = threadIdx.x;
    const int fl = probe_fl(emb);

    if (b >= 256) {                       // ---- decode side-blocks ----
        int bp = b - 256;
        if (bp < 17) {
            int i = bp * 256 + tid;
            if (i < 4096) { int n = i >> 6, k = i & 63; WfT[n * DD + k] = dec1(hW, k * DD + n, fl); }
            else if (i < 4160) hbw[i - 4096] = dec1(hb, i - 4096, fl);
            else if (i < 4224) hbw[64 + (i - 4160)] = dec1(hW, 64 * DD + (i - 4160), fl);
        } else if (bp < 66) {
            int i = (bp - 17) * 256 + tid;
            if (i < 193 * DD) gWf[i] = dec1(gW, i, fl);
            else if (i < 194 * DD) gWf[i] = dec1(gb, i - 193 * DD, fl);
        } else {
            if (tid < DD) linf[tid] = dec1(lW, tid, fl);
            else if (tid == DD) linf[DD] = dec1(lb, 0, fl);
        }
        return;
    }

    __shared__ float sa[4 * DD];
    __shared__ float shs[4 * DD];
    __shared__ unsigned int bmS[128], bmD[128];
    __shared__ int degl[4];
    __shared__ int xl[NN];
    const int lane = tid & 63, wave = tid >> 6;
    const int n0 = b * 4;

    sa[tid] = 0.f;
    if (tid < 128) { bmS[tid] = 0u; bmD[tid] = 0u; }
    if (tid < 4) degl[tid] = 0;
    for (int i = tid; i < NN; i += 256) xl[i] = x[i];
    __syncthreads();

    for (int base = 0; base < EE; base += 2048) {
        int s8[8], d8[8];
#pragma unroll
        for (int u = 0; u < 8; ++u) {
            s8[u] = ei[base + u * 256 + tid];
            d8[u] = ei[EE + base + u * 256 + tid];
        }
#pragma unroll
        for (int u = 0; u < 8; ++u) {
            int s = s8[u], d = d8[u];
            if ((unsigned)(s - n0) < 4u)
                atomicOr(&bmS[(s - n0) * 32 + (d >> 5)], 1u << (d & 31));
            bool md = ((unsigned)(d - n0) < 4u);
            if (md) {
                atomicAdd(&degl[d - n0], 1);
                atomicOr(&bmD[(d - n0) * 32 + (s >> 5)], 1u << (s & 31));
            }
            unsigned long long mask = __ballot(md);
            while (mask) {
                int l = __ffsll(mask) - 1; mask &= mask - 1;
                int sv = __shfl(s, l);
                int dl_ = __shfl(d, l) - n0;
                float hv = dec1(emb, xl[sv] * DD + lane, fl);
                atomicAdd(&sa[dl_ * DD + lane], hv);
            }
        }
    }
    shs[wave * DD + lane] = dec1(emb, xl[n0 + wave] * DD + lane, fl);
    __syncthreads();

    // block-owned bitmap writeout (replaces global zero + atomics)
    if (tid < 128) {
        eim[n0 * 32 + tid] = bmS[tid];
        eimT[n0 * 32 + tid] = bmD[tid];
    }

    // matvec for node n0+wave (raw weight reads, layer 0)
    float inv = 1.f / (float)max(degl[wave], 1);
    float o = dec1(sbl, lane, fl);
    const float* sav = sa + wave * DD;
    const float* shv = shs + wave * DD;
    if (fl) {
        const float* wl = (const float*)sWl;
        const float* wr = (const float*)sWr;
        for (int k = 0; k < DD; ++k)
            o += (sav[k] * inv) * wl[k * DD + lane] + shv[k] * wr[k * DD + lane];
    } else {
        const unsigned short* wl = (const unsigned short*)sWl;
        const unsigned short* wr = (const unsigned short*)sWr;
        for (int k = 0; k < DD; ++k)
            o += (sav[k] * inv) * bfu2f(wl[k * DD + lane]) + shv[k] * bfu2f(wr[k * DD + lane]);
    }
    ln_write(o, n0 + wave, lane, h1, (unsigned short*)nullptr);
}

// =============== K2: SAGE round 1 via edge-scan (gathers h1) ===============
__global__ __launch_bounds__(256) void k_sage1(
        const void* __restrict__ emb, const int* __restrict__ ei,
        const void* __restrict__ sWl, const void* __restrict__ sbl, const void* __restrict__ sWr,
        const float* __restrict__ h1,
        float* __restrict__ h2, unsigned short* __restrict__ hbf) {
    const int b = blockIdx.x, tid = threadIdx.x;
    const int fl = probe_fl(emb);
    __shared__ float sa[4 * DD];
    __shared__ float shs[4 * DD];
    __shared__ int degl[4];
    const int lane = tid & 63, wave = tid >> 6;
    const int n0 = b * 4;

    sa[tid] = 0.f;
    if (tid < 4) degl[tid] = 0;
    __syncthreads();

    for (int base = 0; base < EE; base += 2048) {
        int s8[8], d8[8];
#pragma unroll
        for (int u = 0; u < 8; ++u) {
            s8[u] = ei[base + u * 256 + tid];
            d8[u] = ei[EE + base + u * 256 + tid];
        }
#pragma unroll
        for (int u = 0; u < 8; ++u) {
            int s = s8[u], d = d8[u];
            bool md = ((unsigned)(d - n0) < 4u);
            if (md) atomicAdd(&degl[d - n0], 1);
            unsigned long long mask = __ballot(md);
            while (mask) {
                int l = __ffsll(mask) - 1; mask &= mask - 1;
                int sv = __shfl(s, l);
                int dl_ = __shfl(d, l) - n0;
                float hv = h1[sv * DD + lane];
                atomicAdd(&sa[dl_ * DD + lane], hv);
            }
        }
    }
    shs[wave * DD + lane] = h1[(n0 + wave) * DD + lane];
    __syncthreads();

    // matvec layer 1 (element offsets: W +4096, b +64)
    float inv = 1.f / (float)max(degl[wave], 1);
    float o = dec1(sbl, DD + lane, fl);
    const float* sav = sa + wave * DD;
    const float* shv = shs + wave * DD;
    if (fl) {
        const float* wl = (const float*)sWl + DD * DD;
        const float* wr = (const float*)sWr + DD * DD;
        for (int k = 0; k < DD; ++k)
            o += (sav[k] * inv) * wl[k * DD + lane] + shv[k] * wr[k * DD + lane];
    } else {
        const unsigned short* wl = (const unsigned short*)sWl + DD * DD;
        const unsigned short* wr = (const unsigned short*)sWr + DD * DD;
        for (int k = 0; k < DD; ++k)
            o += (sav[k] * inv) * bfu2f(wl[k * DD + lane]) + shv[k] * bfu2f(wr[k * DD + lane]);
    }
    ln_write(o, n0 + wave, lane, h2, hbf);
}

// =============== K3: B-stage (MFMA) + fused pp/qq projection (verbatim R10) ===============
// NOTE: plain __launch_bounds__(256) — a (256,4) min-waves spec capped VGPR at 64
// and spilled ~100 live values to scratch (R8: WRITE 52 MB, FETCH 373 MB, 2.4x slower).
__global__ __launch_bounds__(256) void k_bstage(
        const float* __restrict__ h2, const unsigned short* __restrict__ hbf,
        const float* __restrict__ WfT, const float* __restrict__ hbw,
        const unsigned int* __restrict__ eim, const unsigned int* __restrict__ eimT,
        const float* __restrict__ gWf,
        float* __restrict__ ppb, float* __restrict__ qqb) {
    __shared__ __align__(16) unsigned short sW[DD * SWP];  // 9216 B
    __shared__ __align__(16) float red[4 * 128];           // 2048 B
    const int b = blockIdx.x, tid = threadIdx.x;
    const int lane = tid & 63, wave = tid >> 6;
    const int l15 = lane & 15, quad = lane >> 4;

    {
        int m = tid >> 2;
        int k0 = (tid & 3) * 16;
        const float* hi = h2 + b * DD;
        const float* wr = WfT + m * DD;
        unsigned short tmp[16];
#pragma unroll
        for (int u = 0; u < 16; ++u) tmp[u] = f2bf_u(hi[k0 + u] * wr[k0 + u]);
        *(short8*)(sW + m * SWP + k0) = *(short8*)tmp;
        *(short8*)(sW + m * SWP + k0 + 8) = *(short8*)(tmp + 8);
    }
    __syncthreads();

    short8 Af[4][2];
#pragma unroll
    for (int mt = 0; mt < 4; ++mt)
#pragma unroll
        for (int kt = 0; kt < 2; ++kt)
            Af[mt][kt] = *(const short8*)(sW + (mt * 16 + l15) * SWP + kt * 32 + quad * 8);

    float hb0[4][4], hww[4][4];
#pragma unroll
    for (int mt = 0; mt < 4; ++mt) {
        f32x4 a = *(const f32x4*)(hbw + mt * 16 + quad * 4);
        f32x4 wv = *(const f32x4*)(hbw + 64 + mt * 16 + quad * 4);
#pragma unroll
        for (int r = 0; r < 4; ++r) { hb0[mt][r] = a[r]; hww[mt][r] = wv[r]; }
    }

    float accf[4][4], accb[4][4];
#pragma unroll
    for (int mt = 0; mt < 4; ++mt)
#pragma unroll
        for (int r = 0; r < 4; ++r) { accf[mt][r] = 0.f; accb[mt][r] = 0.f; }

    int g = wave;
    short8 B0 = *(const short8*)(hbf + (g * 16 + l15) * DD + quad * 8);
    short8 B1 = *(const short8*)(hbf + (g * 16 + l15) * DD + 32 + quad * 8);

    for (int it = 0; it < 16; ++it, g += 4) {
        short8 cB0 = B0, cB1 = B1;
        if (it < 15) {
            int gn = g + 4;
            B0 = *(const short8*)(hbf + (gn * 16 + l15) * DD + quad * 8);
            B1 = *(const short8*)(hbf + (gn * 16 + l15) * DD + 32 + quad * 8);
        }
        unsigned int base = (unsigned int)(b * NN + g * 16);
        unsigned int sf = (eim[base >> 5] >> (base & 31)) & 0xFFFFu;
        unsigned int sb = (eimT[base >> 5] >> (base & 31)) & 0xFFFFu;

        f32x4 C[4];
#pragma unroll
        for (int mt = 0; mt < 4; ++mt)
            C[mt] = (f32x4){hb0[mt][0], hb0[mt][1], hb0[mt][2], hb0[mt][3]};
#pragma unroll
        for (int mt = 0; mt < 4; ++mt)
            C[mt] = __builtin_amdgcn_mfma_f32_16x16x32_bf16(Af[mt][0], cB0, C[mt], 0, 0, 0);
#pragma unroll
        for (int mt = 0; mt < 4; ++mt)
            C[mt] = __builtin_amdgcn_mfma_f32_16x16x32_bf16(Af[mt][1], cB1, C[mt], 0, 0, 0);

        float ef = (float)((sf >> l15) & 1u);
        float s1 = 0.f, s2 = 0.f;
#pragma unroll
        for (int mt = 0; mt < 4; ++mt)
#pragma unroll
            for (int r = 0; r < 4; ++r) {
                float v = C[mt][r] + ef * hww[mt][r];
                C[mt][r] = v;
                s1 += v;
                s2 += v * v;
            }
        s1 += __shfl_xor(s1, 16); s1 += __shfl_xor(s1, 32);
        s2 += __shfl_xor(s2, 16); s2 += __shfl_xor(s2, 32);
        float mean = s1 * (1.f / DD);
        float var = fmaxf(s2 * (1.f / DD) - mean * mean, 0.f);
        float rs = rsqrtf(var + EPSF);
        float mrs = mean * rs;

        if (sf == sb) {
#pragma unroll
            for (int mt = 0; mt < 4; ++mt)
#pragma unroll
                for (int r = 0; r < 4; ++r) {
                    float u = fmaxf(C[mt][r] * rs - mrs, 0.f);
                    accf[mt][r] += u;
                    accb[mt][r] += u;
                }
        } else {
#pragma unroll
            for (int mt = 0; mt < 4; ++mt)
#pragma unroll
                for (int r = 0; r < 4; ++r)
                    accf[mt][r] += fmaxf(C[mt][r] * rs - mrs, 0.f);
            float de = (float)((sb >> l15) & 1u) - ef;
            float t1 = 0.f, t2 = 0.f;
#pragma unroll
            for (int mt = 0; mt < 4; ++mt)
#pragma unroll
                for (int r = 0; r < 4; ++r) {
                    float v = C[mt][r] + de * hww[mt][r];
                    C[mt][r] = v;
                    t1 += v;
                    t2 += v * v;
                }
            t1 += __shfl_xor(t1, 16); t1 += __shfl_xor(t1, 32);
            t2 += __shfl_xor(t2, 16); t2 += __shfl_xor(t2, 32);
            float mean2 = t1 * (1.f / DD);
            float var2 = fmaxf(t2 * (1.f / DD) - mean2 * mean2, 0.f);
            float rs2 = rsqrtf(var2 + EPSF);
            float mrs2 = mean2 * rs2;
#pragma unroll
            for (int mt = 0; mt < 4; ++mt)
#pragma unroll
                for (int r = 0; r < 4; ++r)
                    accb[mt][r] += fmaxf(C[mt][r] * rs2 - mrs2, 0.f);
        }
    }

#pragma unroll
    for (int step = 1; step < 16; step <<= 1)
#pragma unroll
        for (int mt = 0; mt < 4; ++mt)
#pragma unroll
            for (int r = 0; r < 4; ++r) {
                accf[mt][r] += __shfl_xor(accf[mt][r], step);
                accb[mt][r] += __shfl_xor(accb[mt][r], step);
            }
    if (l15 == 0) {
#pragma unroll
        for (int mt = 0; mt < 4; ++mt)
#pragma unroll
            for (int r = 0; r < 4; ++r) {
                int m = mt * 16 + quad * 4 + r;
                red[wave * 128 + m] = accf[mt][r];
                red[wave * 128 + DD + m] = accb[mt][r];
            }
    }
    __syncthreads();
    if (tid < 128) {
        float sum = red[tid] + red[128 + tid] + red[256 + tid] + red[384 + tid];
        red[tid] = sum;
    }
    __syncthreads();
    if (wave < 2) {
        const float* sv = red + wave * DD;
        int row0 = wave ? 129 : 65;
        float o = 0.f;
        for (int k = 0; k < DD; ++k) o += sv[k] * gWf[(row0 + k) * DD + lane];
        (wave ? qqb : ppb)[b * DD + lane] = o;
    }
}

// =============== K4: final selected pairs (MFMA, verbatim R10) ===============
__global__ __launch_bounds__(256) void k_final(
        const void* __restrict__ emb,
        const int* __restrict__ pos, const unsigned short* __restrict__ hbf,
        const float* __restrict__ gWf, const unsigned int* __restrict__ eim,
        const float* __restrict__ ppb, const float* __restrict__ qqb,
        const float* __restrict__ linf, void* __restrict__ outv) {
    __shared__ __align__(16) unsigned short sgW[DD * SWP];
    const int b = blockIdx.x, tid = threadIdx.x;
    const int lane = tid & 63, wave = tid >> 6;
    const int l15 = lane & 15, quad = lane >> 4;
    const int fl = probe_fl(emb);

    {
        int m = tid >> 2;
        int k0 = (tid & 3) * 16;
        unsigned short tmp[16];
#pragma unroll
        for (int u = 0; u < 16; ++u) tmp[u] = f2bf_u(gWf[(k0 + u) * DD + m]);
        *(short8*)(sgW + m * SWP + k0) = *(short8*)tmp;
        *(short8*)(sgW + m * SWP + k0 + 8) = *(short8*)(tmp + 8);
    }

    int pp_ = b * 64 + wave * 16 + l15;
    int a = pos[2 * pp_], bb = pos[2 * pp_ + 1];
    short8 ha0 = *(const short8*)(hbf + a * DD + quad * 8);
    short8 hb0v = *(const short8*)(hbf + bb * DD + quad * 8);
    short8 ha1 = *(const short8*)(hbf + a * DD + 32 + quad * 8);
    short8 hb1v = *(const short8*)(hbf + bb * DD + 32 + quad * 8);
    short8 B0, B1;
#pragma unroll
    for (int j = 0; j < 8; ++j) {
        B0[j] = (short)f2bf_u(bfu2f((unsigned short)ha0[j]) * bfu2f((unsigned short)hb0v[j]));
        B1[j] = (short)f2bf_u(bfu2f((unsigned short)ha1[j]) * bfu2f((unsigned short)hb1v[j]));
    }
    __syncthreads();

    f32x4 C[4];
#pragma unroll
    for (int mt = 0; mt < 4; ++mt) C[mt] = (f32x4){0.f, 0.f, 0.f, 0.f};
#pragma unroll
    for (int mt = 0; mt < 4; ++mt) {
        short8 A0 = *(const short8*)(sgW + (mt * 16 + l15) * SWP + quad * 8);
        C[mt] = __builtin_amdgcn_mfma_f32_16x16x32_bf16(A0, B0, C[mt], 0, 0, 0);
    }
#pragma unroll
    for (int mt = 0; mt < 4; ++mt) {
        short8 A1 = *(const short8*)(sgW + (mt * 16 + l15) * SWP + 32 + quad * 8);
        C[mt] = __builtin_amdgcn_mfma_f32_16x16x32_bf16(A1, B1, C[mt], 0, 0, 0);
    }

    unsigned int iab = (unsigned int)(a * NN + bb), iba = (unsigned int)(bb * NN + a);
    float eab = (float)((eim[iab >> 5] >> (iab & 31)) & 1u);
    float eba = (float)((eim[iba >> 5] >> (iba & 31)) & 1u);

    float u1[4][4], u2[4][4];
    float s1 = 0.f, s12 = 0.f, s2 = 0.f, s22 = 0.f;
#pragma unroll
    for (int mt = 0; mt < 4; ++mt) {
        int m0 = mt * 16 + quad * 4;
        f32x4 w64v = *(const f32x4*)(gWf + 64 * DD + m0);
        f32x4 gbv  = *(const f32x4*)(gWf + 193 * DD + m0);
        f32x4 ppa  = *(const f32x4*)(ppb + a * DD + m0);
        f32x4 qqb_ = *(const f32x4*)(qqb + bb * DD + m0);
        f32x4 ppb_ = *(const f32x4*)(ppb + bb * DD + m0);
        f32x4 qqa  = *(const f32x4*)(qqb + a * DD + m0);
#pragma unroll
        for (int r = 0; r < 4; ++r) {
            float v1 = C[mt][r] + eab * w64v[r] + ppa[r] + qqb_[r] + gbv[r];
            float v2 = C[mt][r] + eba * w64v[r] + ppb_[r] + qqa[r] + gbv[r];
            u1[mt][r] = v1; u2[mt][r] = v2;
            s1 += v1; s12 += v1 * v1;
            s2 += v2; s22 += v2 * v2;
        }
    }
    s1 += __shfl_xor(s1, 16);  s1 += __shfl_xor(s1, 32);
    s12 += __shfl_xor(s12, 16); s12 += __shfl_xor(s12, 32);
    s2 += __shfl_xor(s2, 16);  s2 += __shfl_xor(s2, 32);
    s22 += __shfl_xor(s22, 16); s22 += __shfl_xor(s22, 32);
    float mean1 = s1 * (1.f / DD);
    float rs1 = rsqrtf(fmaxf(s12 * (1.f / DD) - mean1 * mean1, 0.f) + EPSF);
    float mrs1 = mean1 * rs1;
    float mean2 = s2 * (1.f / DD);
    float rs2 = rsqrtf(fmaxf(s22 * (1.f / DD) - mean2 * mean2, 0.f) + EPSF);
    float mrs2 = mean2 * rs2;

    float r = 0.f;
#pragma unroll
    for (int mt = 0; mt < 4; ++mt) {
        f32x4 lw = *(const f32x4*)(linf + mt * 16 + quad * 4);
#pragma unroll
        for (int rr = 0; rr < 4; ++rr) {
            float g1 = fmaxf(u1[mt][rr] * rs1 - mrs1, 0.f);
            float g2 = fmaxf(u2[mt][rr] * rs2 - mrs2, 0.f);
            r += g1 * g2 * lw[rr];
        }
    }
    r += __shfl_xor(r, 16); r += __shfl_xor(r, 32);
    if (quad == 0) {
        float res = r + linf[DD];
        if (fl) ((float*)outv)[pp_] = res;
        else    ((bf16*)outv)[pp_] = __float2bfloat16(res);
    }
}

extern "C" void kernel_launch(void* const* d_in, const int* in_sizes, int n_in,
                              void* d_out, int out_size, void* d_ws, size_t ws_size,
                              hipStream_t stream) {
    const int* x   = (const int*)d_in[0];
    const int* ei  = (const int*)d_in[1];
    const int* pos = (const int*)d_in[2];
    const void* emb = d_in[3];

    char* w = (char*)d_ws;
    auto alloc = [&](size_t bytes) {
        void* q = (void*)w;
        w += (bytes + 255) & ~(size_t)255;
        return q;
    };
    unsigned int* eim  = (unsigned int*)alloc(NN * NN / 8);
    unsigned int* eimT = (unsigned int*)alloc(NN * NN / 8);
    float* h1   = (float*)alloc(NN * DD * 4);
    float* h2   = (float*)alloc(NN * DD * 4);
    unsigned short* hbf = (unsigned short*)alloc(NN * DD * 2);
    float* WfT  = (float*)alloc(DD * DD * 4);
    float* hbw  = (float*)alloc(128 * 4);
    float* gWf  = (float*)alloc(194 * DD * 4);
    float* linf = (float*)alloc(65 * 4);
    float* ppb  = (float*)alloc(NN * DD * 4);
    float* qqb  = (float*)alloc(NN * DD * 4);

    k_sage0<<<323, 256, 0, stream>>>(emb, x, ei, d_in[4], d_in[5], d_in[6],
                                     d_in[7], d_in[8], d_in[9], d_in[10],
                                     d_in[11], d_in[12],
                                     h1, eim, eimT, WfT, hbw, gWf, linf);
    k_sage1<<<256, 256, 0, stream>>>(emb, ei, d_in[4], d_in[5], d_in[6], h1, h2, hbf);
    k_bstage<<<NN, 256, 0, stream>>>(h2, hbf, WfT, hbw, eim, eimT, gWf, ppb, qqb);
    k_final<<<PP / 64, 256, 0, stream>>>(emb, pos, hbf, gWf, eim, ppb, qqb, linf, d_out);
}

// Round 12
// 168.668 us; speedup vs baseline: 1.0321x; 1.0321x over previous
//
#include <hip/hip_runtime.h>
#include <hip/hip_bf16.h>

#define NN 1024
#define DD 64
#define EE 16384
#define PP 8192
#define EPSF 1e-5f
#define SWP (DD + 8)   // padded LDS row stride in shorts (144 B)

typedef __hip_bfloat16 bf16;
typedef __attribute__((ext_vector_type(8))) short short8;
typedef __attribute__((ext_vector_type(4))) float f32x4;

static __device__ __forceinline__ float dec1(const void* src, int i, int fl) {
    if (fl) return ((const float*)src)[i];
    return __bfloat162float(((const bf16*)src)[i]);
}
static __device__ __forceinline__ unsigned short f2bf_u(float f) {
    bf16 h = __float2bfloat16(f);
    return *reinterpret_cast<unsigned short*>(&h);
}
static __device__ __forceinline__ float bfu2f(unsigned short u) {
    return __uint_as_float(((unsigned int)u) << 16);
}
static __device__ __forceinline__ int probe_fl(const void* emb) {
    int lane = threadIdx.x & 63;
    unsigned short raw = ((const unsigned short*)emb)[lane];
    float v = __uint_as_float(((unsigned int)raw) << 16);
    return (__ballot(!(fabsf(v) <= 1e3f)) != 0ull) ? 1 : 0;
}

// =============== K1: decode everything + embed + zero bitmaps + CSR build ===============
// (R10 verbatim — measured good. CSR loops register-batched per R9 lesson.)
__global__ __launch_bounds__(256) void k_prep(
        const void* __restrict__ emb, const void* __restrict__ sWl,
        const void* __restrict__ sbl, const void* __restrict__ sWr,
        const void* __restrict__ hW, const void* __restrict__ hb,
        const void* __restrict__ gW, const void* __restrict__ gb,
        const void* __restrict__ lW, const void* __restrict__ lb,
        const int* __restrict__ x, const int* __restrict__ ei,
        float* __restrict__ Wlf, float* __restrict__ blf, float* __restrict__ Wrf,
        float* __restrict__ WfT, float* __restrict__ hbw,
        float* __restrict__ gWf, float* __restrict__ linf,
        float* __restrict__ h0,
        unsigned int* __restrict__ eim, unsigned int* __restrict__ eimT,
        int* __restrict__ rowptr, int* __restrict__ csrc) {
    __shared__ int sdeg[NN];
    __shared__ int stmp[256];
    const int b = blockIdx.x, tid = threadIdx.x;
    const int fl = probe_fl(emb);

    if (b < 256) {
        int z = b * 256 + tid;
        if (z < 32768) eim[z] = 0u;
        else           eimT[z - 32768] = 0u;
    }

    if (b < 32) { int i = b * 256 + tid; Wlf[i] = dec1(sWl, i, fl); }
    else if (b == 32) { if (tid < 128) blf[tid] = dec1(sbl, tid, fl); }
    else if (b < 65) { int i = (b - 33) * 256 + tid; Wrf[i] = dec1(sWr, i, fl); }
    else if (b < 82) {
        int i = (b - 65) * 256 + tid;
        if (i < 4096) { int n = i >> 6, k = i & 63; WfT[n * DD + k] = dec1(hW, k * DD + n, fl); }
        else if (i < 4160) hbw[i - 4096] = dec1(hb, i - 4096, fl);
        else if (i < 4224) hbw[64 + (i - 4160)] = dec1(hW, 64 * DD + (i - 4160), fl);
    } else if (b < 131) {
        int i = (b - 82) * 256 + tid;
        if (i < 193 * DD) gWf[i] = dec1(gW, i, fl);
        else if (i < 194 * DD) gWf[i] = dec1(gb, i - 193 * DD, fl);
    } else if (b == 131) {
        if (tid < DD) linf[tid] = dec1(lW, tid, fl);
        else if (tid == DD) linf[DD] = dec1(lb, 0, fl);
    } else if (b < 388) {
        int i = (b - 132) * 256 + tid;
        int node = i >> 6, f = i & 63;
        h0[i] = dec1(emb, x[node] * DD + f, fl);
    } else if (b == 388) {
        for (int i = tid; i < NN; i += 256) sdeg[i] = 0;
        __syncthreads();
        for (int base = 0; base < EE; base += 2048) {
            int d8[8];
#pragma unroll
            for (int u = 0; u < 8; ++u) d8[u] = ei[EE + base + u * 256 + tid];
#pragma unroll
            for (int u = 0; u < 8; ++u) atomicAdd(&sdeg[d8[u]], 1);
        }
        __syncthreads();
        int base4 = tid * 4;
        int v[4]; int s = 0;
#pragma unroll
        for (int u = 0; u < 4; ++u) { v[u] = sdeg[base4 + u]; s += v[u]; }
        stmp[tid] = s;
        __syncthreads();
        for (int off = 1; off < 256; off <<= 1) {
            int a = (tid >= off) ? stmp[tid - off] : 0;
            __syncthreads();
            stmp[tid] += a;
            __syncthreads();
        }
        int run = stmp[tid] - s;
#pragma unroll
        for (int u = 0; u < 4; ++u) {
            rowptr[base4 + u] = run;
            sdeg[base4 + u] = run;
            run += v[u];
        }
        if (tid == 255) rowptr[NN] = run;
        __syncthreads();
        for (int base = 0; base < EE; base += 2048) {
            int d8[8], s8[8];
#pragma unroll
            for (int u = 0; u < 8; ++u) {
                d8[u] = ei[EE + base + u * 256 + tid];
                s8[u] = ei[base + u * 256 + tid];
            }
#pragma unroll
            for (int u = 0; u < 8; ++u) {
                int c = atomicAdd(&sdeg[d8[u]], 1);
                csrc[c] = s8[u];
            }
        }
    }
}

// =============== shared SAGE body (one wave per node) ===============
static __device__ __forceinline__ void sage_body(
        char* smem, int node, int lane, int wave,
        const int* __restrict__ rowptr, const int* __restrict__ csrc,
        const float* __restrict__ hin,
        const float* __restrict__ Wl, const float* __restrict__ bl,
        const float* __restrict__ Wr,
        float* __restrict__ hout, unsigned short* __restrict__ hbf) {
    float* sa = (float*)smem + wave * 2 * DD;
    float* sh = sa + DD;
    int r0 = rowptr[node], r1 = rowptr[node + 1];
    float s = 0.f;
    for (int r = r0; r < r1; ++r) s += hin[csrc[r] * DD + lane];
    sa[lane] = s / (float)max(r1 - r0, 1);
    sh[lane] = hin[node * DD + lane];
    float o = bl[lane];
    for (int k = 0; k < DD; ++k)
        o += sa[k] * Wl[k * DD + lane] + sh[k] * Wr[k * DD + lane];
    float m = o;
    for (int off = 32; off; off >>= 1) m += __shfl_xor(m, off);
    m *= (1.f / DD);
    float d0 = o - m;
    float v = d0 * d0;
    for (int off = 32; off; off >>= 1) v += __shfl_xor(v, off);
    v *= (1.f / DD);
    float r = d0 * rsqrtf(v + EPSF);
    hout[node * DD + lane] = r;
    if (hbf) hbf[node * DD + lane] = f2bf_u(r);
}

// =============== K2: SAGE round 0 + edge-bitmap atomics ===============
__global__ __launch_bounds__(256) void k_sage0(
        const int* __restrict__ ei,
        const int* __restrict__ rowptr, const int* __restrict__ csrc,
        const float* __restrict__ h0,
        const float* __restrict__ Wlf, const float* __restrict__ blf,
        const float* __restrict__ Wrf,
        float* __restrict__ h1,
        unsigned int* __restrict__ eim, unsigned int* __restrict__ eimT) {
    __shared__ __align__(16) char smem[4 * 2 * DD * 4];
    const int b = blockIdx.x, tid = threadIdx.x;
    const int lane = tid & 63, wave = tid >> 6;
    if (tid < 64) {
        int e = b * 64 + tid;
        int s = ei[e], d = ei[EE + e];
        unsigned int idx = (unsigned int)(s * NN + d);
        atomicOr(&eim[idx >> 5], 1u << (idx & 31));
        unsigned int idxT = (unsigned int)(d * NN + s);
        atomicOr(&eimT[idxT >> 5], 1u << (idxT & 31));
    }
    sage_body(smem, b * 4 + wave, lane, wave, rowptr, csrc, h0, Wlf, blf, Wrf,
              h1, (unsigned short*)nullptr);
}

// =============== K3: SAGE round 1 (writes h2 + bf16 copy) ===============
__global__ __launch_bounds__(256) void k_sage1(
        const int* __restrict__ rowptr, const int* __restrict__ csrc,
        const float* __restrict__ h1,
        const float* __restrict__ Wlf, const float* __restrict__ blf,
        const float* __restrict__ Wrf,
        float* __restrict__ h2, unsigned short* __restrict__ hbf) {
    __shared__ __align__(16) char smem[4 * 2 * DD * 4];
    const int b = blockIdx.x, tid = threadIdx.x;
    const int lane = tid & 63, wave = tid >> 6;
    sage_body(smem, b * 4 + wave, lane, wave, rowptr, csrc, h1,
              Wlf + DD * DD, blf + DD, Wrf + DD * DD, h2, hbf);
}

// =============== per-16x16-tile LN epilogue (shared by both unrolled groups) ===============
static __device__ __forceinline__ void tile_ln(
        f32x4* C, unsigned int sf, unsigned int sb, int l15,
        const float hww[4][4], float accf[4][4], float accb[4][4]) {
    float ef = (float)((sf >> l15) & 1u);
    float s1 = 0.f, s2 = 0.f;
#pragma unroll
    for (int mt = 0; mt < 4; ++mt)
#pragma unroll
        for (int r = 0; r < 4; ++r) {
            float v = C[mt][r] + ef * hww[mt][r];
            C[mt][r] = v;
            s1 += v;
            s2 += v * v;
        }
    s1 += __shfl_xor(s1, 16); s1 += __shfl_xor(s1, 32);
    s2 += __shfl_xor(s2, 16); s2 += __shfl_xor(s2, 32);
    float mean = s1 * (1.f / DD);
    float var = fmaxf(s2 * (1.f / DD) - mean * mean, 0.f);
    float rs = rsqrtf(var + EPSF);
    float mrs = mean * rs;

    if (sf == sb) {
#pragma unroll
        for (int mt = 0; mt < 4; ++mt)
#pragma unroll
            for (int r = 0; r < 4; ++r) {
                float u = fmaxf(C[mt][r] * rs - mrs, 0.f);
                accf[mt][r] += u;
                accb[mt][r] += u;
            }
    } else {
#pragma unroll
        for (int mt = 0; mt < 4; ++mt)
#pragma unroll
            for (int r = 0; r < 4; ++r)
                accf[mt][r] += fmaxf(C[mt][r] * rs - mrs, 0.f);
        float de = (float)((sb >> l15) & 1u) - ef;
        float t1 = 0.f, t2 = 0.f;
#pragma unroll
        for (int mt = 0; mt < 4; ++mt)
#pragma unroll
            for (int r = 0; r < 4; ++r) {
                float v = C[mt][r] + de * hww[mt][r];
                C[mt][r] = v;
                t1 += v;
                t2 += v * v;
            }
        t1 += __shfl_xor(t1, 16); t1 += __shfl_xor(t1, 32);
        t2 += __shfl_xor(t2, 16); t2 += __shfl_xor(t2, 32);
        float mean2 = t1 * (1.f / DD);
        float var2 = fmaxf(t2 * (1.f / DD) - mean2 * mean2, 0.f);
        float rs2 = rsqrtf(var2 + EPSF);
        float mrs2 = mean2 * rs2;
#pragma unroll
        for (int mt = 0; mt < 4; ++mt)
#pragma unroll
            for (int r = 0; r < 4; ++r)
                accb[mt][r] += fmaxf(C[mt][r] * rs2 - mrs2, 0.f);
    }
}

// =============== K4: B-stage (MFMA), 2 blocks/node, 2 j-groups per iteration ===============
// R11 counters: MfmaUtil 7%, VALU 48%, occ 17% -> latency-bound on LN shuffle chains.
// Unroll-2 gives two independent shuffle chains per iteration (ILP x2) and 16
// back-to-back MFMAs; groups (g, g+1) with g even share one eim/eimT word.
// NOTE: plain __launch_bounds__(256) — a (256,4) min-waves spec capped VGPR at 64
// and spilled (R8: WRITE 52 MB, FETCH 373 MB, 2.4x slower).
__global__ __launch_bounds__(256) void k_bstage(
        const float* __restrict__ h2, const unsigned short* __restrict__ hbf,
        const float* __restrict__ WfT, const float* __restrict__ hbw,
        const unsigned int* __restrict__ eim, const unsigned int* __restrict__ eimT,
        float* __restrict__ vpp, float* __restrict__ vqp) {
    __shared__ __align__(16) unsigned short sW[DD * SWP];  // 9216 B
    __shared__ __align__(16) float red[4 * 128];           // 2048 B
    const int bid = blockIdx.x;
    const int fix = bid >> 1, half = bid & 1;
    const int tid = threadIdx.x;
    const int lane = tid & 63, wave = tid >> 6;
    const int l15 = lane & 15, quad = lane >> 4;

    {
        int m = tid >> 2;
        int k0 = (tid & 3) * 16;
        const float* hi = h2 + fix * DD;
        const float* wr = WfT + m * DD;
        unsigned short tmp[16];
#pragma unroll
        for (int u = 0; u < 16; ++u) tmp[u] = f2bf_u(hi[k0 + u] * wr[k0 + u]);
        *(short8*)(sW + m * SWP + k0) = *(short8*)tmp;
        *(short8*)(sW + m * SWP + k0 + 8) = *(short8*)(tmp + 8);
    }
    __syncthreads();

    short8 Af[4][2];
#pragma unroll
    for (int mt = 0; mt < 4; ++mt)
#pragma unroll
        for (int kt = 0; kt < 2; ++kt)
            Af[mt][kt] = *(const short8*)(sW + (mt * 16 + l15) * SWP + kt * 32 + quad * 8);

    float hb0[4][4], hww[4][4];
#pragma unroll
    for (int mt = 0; mt < 4; ++mt) {
        f32x4 a = *(const f32x4*)(hbw + mt * 16 + quad * 4);
        f32x4 wv = *(const f32x4*)(hbw + 64 + mt * 16 + quad * 4);
#pragma unroll
        for (int r = 0; r < 4; ++r) { hb0[mt][r] = a[r]; hww[mt][r] = wv[r]; }
    }

    float accf[4][4], accb[4][4];
#pragma unroll
    for (int mt = 0; mt < 4; ++mt)
#pragma unroll
        for (int r = 0; r < 4; ++r) { accf[mt][r] = 0.f; accb[mt][r] = 0.f; }

    const int g0 = half * 32 + wave * 8;   // 8 consecutive groups; pairs start even
    short8 B0a = *(const short8*)(hbf + (g0 * 16 + l15) * DD + quad * 8);
    short8 B1a = *(const short8*)(hbf + (g0 * 16 + l15) * DD + 32 + quad * 8);
    short8 B0b = *(const short8*)(hbf + ((g0 + 1) * 16 + l15) * DD + quad * 8);
    short8 B1b = *(const short8*)(hbf + ((g0 + 1) * 16 + l15) * DD + 32 + quad * 8);

    for (int it = 0; it < 4; ++it) {
        int g = g0 + it * 2;
        short8 cB0a = B0a, cB1a = B1a, cB0b = B0b, cB1b = B1b;
        if (it < 3) {
            int gn = g + 2;
            B0a = *(const short8*)(hbf + (gn * 16 + l15) * DD + quad * 8);
            B1a = *(const short8*)(hbf + (gn * 16 + l15) * DD + 32 + quad * 8);
            B0b = *(const short8*)(hbf + ((gn + 1) * 16 + l15) * DD + quad * 8);
            B1b = *(const short8*)(hbf + ((gn + 1) * 16 + l15) * DD + 32 + quad * 8);
        }
        unsigned int widx = (unsigned int)(fix * NN + g * 16) >> 5;  // g even -> word-aligned
        unsigned int wf = eim[widx];
        unsigned int wb = eimT[widx];

        f32x4 Ca[4], Cb[4];
#pragma unroll
        for (int mt = 0; mt < 4; ++mt) {
            Ca[mt] = (f32x4){hb0[mt][0], hb0[mt][1], hb0[mt][2], hb0[mt][3]};
            Cb[mt] = Ca[mt];
        }
#pragma unroll
        for (int mt = 0; mt < 4; ++mt)
            Ca[mt] = __builtin_amdgcn_mfma_f32_16x16x32_bf16(Af[mt][0], cB0a, Ca[mt], 0, 0, 0);
#pragma unroll
        for (int mt = 0; mt < 4; ++mt)
            Ca[mt] = __builtin_amdgcn_mfma_f32_16x16x32_bf16(Af[mt][1], cB1a, Ca[mt], 0, 0, 0);
#pragma unroll
        for (int mt = 0; mt < 4; ++mt)
            Cb[mt] = __builtin_amdgcn_mfma_f32_16x16x32_bf16(Af[mt][0], cB0b, Cb[mt], 0, 0, 0);
#pragma unroll
        for (int mt = 0; mt < 4; ++mt)
            Cb[mt] = __builtin_amdgcn_mfma_f32_16x16x32_bf16(Af[mt][1], cB1b, Cb[mt], 0, 0, 0);

        tile_ln(Ca, wf & 0xFFFFu, wb & 0xFFFFu, l15, hww, accf, accb);
        tile_ln(Cb, wf >> 16, wb >> 16, l15, hww, accf, accb);
    }

#pragma unroll
    for (int step = 1; step < 16; step <<= 1)
#pragma unroll
        for (int mt = 0; mt < 4; ++mt)
#pragma unroll
            for (int r = 0; r < 4; ++r) {
                accf[mt][r] += __shfl_xor(accf[mt][r], step);
                accb[mt][r] += __shfl_xor(accb[mt][r], step);
            }
    if (l15 == 0) {
#pragma unroll
        for (int mt = 0; mt < 4; ++mt)
#pragma unroll
            for (int r = 0; r < 4; ++r) {
                int m = mt * 16 + quad * 4 + r;
                red[wave * 128 + m] = accf[mt][r];
                red[wave * 128 + DD + m] = accb[mt][r];
            }
    }
    __syncthreads();
    if (tid < 2 * DD) {
        float sum = red[tid] + red[128 + tid] + red[256 + tid] + red[384 + tid];
        if (tid < DD) vpp[(half * NN + fix) * DD + tid] = sum;
        else          vqp[(half * NN + fix) * DD + (tid - DD)] = sum;
    }
}

// =============== K5: per-node projections (sums the two bstage partials) ===============
__global__ void k_ppqq2(const float* __restrict__ vpp, const float* __restrict__ vqp,
                        const float* __restrict__ gWf,
                        float* __restrict__ ppb, float* __restrict__ qqb) {
    int b = blockIdx.x;
    int f = threadIdx.x;
    int i = b & 1023, which = b >> 10;
    const float* part = which ? vqp : vpp;
    int row0 = which ? 129 : 65;
    __shared__ float sv[DD];
    sv[f] = part[i * DD + f] + part[(NN + i) * DD + f];
    __syncthreads();
    float o = 0.f;
    for (int k = 0; k < DD; ++k) o += sv[k] * gWf[(row0 + k) * DD + f];
    (which ? qqb : ppb)[i * DD + f] = o;
}

// =============== K6: final selected pairs (MFMA, verbatim R10) ===============
__global__ __launch_bounds__(256) void k_final(
        const void* __restrict__ emb,
        const int* __restrict__ pos, const unsigned short* __restrict__ hbf,
        const float* __restrict__ gWf, const unsigned int* __restrict__ eim,
        const float* __restrict__ ppb, const float* __restrict__ qqb,
        const float* __restrict__ linf, void* __restrict__ outv) {
    __shared__ __align__(16) unsigned short sgW[DD * SWP];
    const int b = blockIdx.x, tid = threadIdx.x;
    const int lane = tid & 63, wave = tid >> 6;
    const int l15 = lane & 15, quad = lane >> 4;
    const int fl = probe_fl(emb);

    {
        int m = tid >> 2;
        int k0 = (tid & 3) * 16;
        unsigned short tmp[16];
#pragma unroll
        for (int u = 0; u < 16; ++u) tmp[u] = f2bf_u(gWf[(k0 + u) * DD + m]);
        *(short8*)(sgW + m * SWP + k0) = *(short8*)tmp;
        *(short8*)(sgW + m * SWP + k0 + 8) = *(short8*)(tmp + 8);
    }

    int pp_ = b * 64 + wave * 16 + l15;
    int a = pos[2 * pp_], bb = pos[2 * pp_ + 1];
    short8 ha0 = *(const short8*)(hbf + a * DD + quad * 8);
    short8 hb0v = *(const short8*)(hbf + bb * DD + quad * 8);
    short8 ha1 = *(const short8*)(hbf + a * DD + 32 + quad * 8);
    short8 hb1v = *(const short8*)(hbf + bb * DD + 32 + quad * 8);
    short8 B0, B1;
#pragma unroll
    for (int j = 0; j < 8; ++j) {
        B0[j] = (short)f2bf_u(bfu2f((unsigned short)ha0[j]) * bfu2f((unsigned short)hb0v[j]));
        B1[j] = (short)f2bf_u(bfu2f((unsigned short)ha1[j]) * bfu2f((unsigned short)hb1v[j]));
    }
    __syncthreads();

    f32x4 C[4];
#pragma unroll
    for (int mt = 0; mt < 4; ++mt) C[mt] = (f32x4){0.f, 0.f, 0.f, 0.f};
#pragma unroll
    for (int mt = 0; mt < 4; ++mt) {
        short8 A0 = *(const short8*)(sgW + (mt * 16 + l15) * SWP + quad * 8);
        C[mt] = __builtin_amdgcn_mfma_f32_16x16x32_bf16(A0, B0, C[mt], 0, 0, 0);
    }
#pragma unroll
    for (int mt = 0; mt < 4; ++mt) {
        short8 A1 = *(const short8*)(sgW + (mt * 16 + l15) * SWP + 32 + quad * 8);
        C[mt] = __builtin_amdgcn_mfma_f32_16x16x32_bf16(A1, B1, C[mt], 0, 0, 0);
    }

    unsigned int iab = (unsigned int)(a * NN + bb), iba = (unsigned int)(bb * NN + a);
    float eab = (float)((eim[iab >> 5] >> (iab & 31)) & 1u);
    float eba = (float)((eim[iba >> 5] >> (iba & 31)) & 1u);

    float u1[4][4], u2[4][4];
    float s1 = 0.f, s12 = 0.f, s2 = 0.f, s22 = 0.f;
#pragma unroll
    for (int mt = 0; mt < 4; ++mt) {
        int m0 = mt * 16 + quad * 4;
        f32x4 w64v = *(const f32x4*)(gWf + 64 * DD + m0);
        f32x4 gbv  = *(const f32x4*)(gWf + 193 * DD + m0);
        f32x4 ppa  = *(const f32x4*)(ppb + a * DD + m0);
        f32x4 qqb_ = *(const f32x4*)(qqb + bb * DD + m0);
        f32x4 ppb_ = *(const f32x4*)(ppb + bb * DD + m0);
        f32x4 qqa  = *(const f32x4*)(qqb + a * DD + m0);
#pragma unroll
        for (int r = 0; r < 4; ++r) {
            float v1 = C[mt][r] + eab * w64v[r] + ppa[r] + qqb_[r] + gbv[r];
            float v2 = C[mt][r] + eba * w64v[r] + ppb_[r] + qqa[r] + gbv[r];
            u1[mt][r] = v1; u2[mt][r] = v2;
            s1 += v1; s12 += v1 * v1;
            s2 += v2; s22 += v2 * v2;
        }
    }
    s1 += __shfl_xor(s1, 16);  s1 += __shfl_xor(s1, 32);
    s12 += __shfl_xor(s12, 16); s12 += __shfl_xor(s12, 32);
    s2 += __shfl_xor(s2, 16);  s2 += __shfl_xor(s2, 32);
    s22 += __shfl_xor(s22, 16); s22 += __shfl_xor(s22, 32);
    float mean1 = s1 * (1.f / DD);
    float rs1 = rsqrtf(fmaxf(s12 * (1.f / DD) - mean1 * mean1, 0.f) + EPSF);
    float mrs1 = mean1 * rs1;
    float mean2 = s2 * (1.f / DD);
    float rs2 = rsqrtf(fmaxf(s22 * (1.f / DD) - mean2 * mean2, 0.f) + EPSF);
    float mrs2 = mean2 * rs2;

    float r = 0.f;
#pragma unroll
    for (int mt = 0; mt < 4; ++mt) {
        f32x4 lw = *(const f32x4*)(linf + mt * 16 + quad * 4);
#pragma unroll
        for (int rr = 0; rr < 4; ++rr) {
            float g1 = fmaxf(u1[mt][rr] * rs1 - mrs1, 0.f);
            float g2 = fmaxf(u2[mt][rr] * rs2 - mrs2, 0.f);
            r += g1 * g2 * lw[rr];
        }
    }
    r += __shfl_xor(r, 16); r += __shfl_xor(r, 32);
    if (quad == 0) {
        float res = r + linf[DD];
        if (fl) ((float*)outv)[pp_] = res;
        else    ((bf16*)outv)[pp_] = __float2bfloat16(res);
    }
}

extern "C" void kernel_launch(void* const* d_in, const int* in_sizes, int n_in,
                              void* d_out, int out_size, void* d_ws, size_t ws_size,
                              hipStream_t stream) {
    const int* x   = (const int*)d_in[0];
    const int* ei  = (const int*)d_in[1];
    const int* pos = (const int*)d_in[2];
    const void* emb = d_in[3];

    char* w = (char*)d_ws;
    auto alloc = [&](size_t bytes) {
        void* q = (void*)w;
        w += (bytes + 255) & ~(size_t)255;
        return q;
    };
    unsigned int* eim  = (unsigned int*)alloc(NN * NN / 8);
    unsigned int* eimT = (unsigned int*)alloc(NN * NN / 8);
    float* h0   = (float*)alloc(NN * DD * 4);
    float* h1   = (float*)alloc(NN * DD * 4);
    float* h2   = (float*)alloc(NN * DD * 4);
    unsigned short* hbf = (unsigned short*)alloc(NN * DD * 2);
    float* Wlf  = (float*)alloc(2 * DD * DD * 4);
    float* blf  = (float*)alloc(2 * DD * 4);
    float* Wrf  = (float*)alloc(2 * DD * DD * 4);
    float* WfT  = (float*)alloc(DD * DD * 4);
    float* hbw  = (float*)alloc(128 * 4);
    float* gWf  = (float*)alloc(194 * DD * 4);
    float* linf = (float*)alloc(65 * 4);
    float* vpp  = (float*)alloc(2 * NN * DD * 4);
    float* vqp  = (float*)alloc(2 * NN * DD * 4);
    float* ppb  = (float*)alloc(NN * DD * 4);
    float* qqb  = (float*)alloc(NN * DD * 4);
    int* rowptr = (int*)alloc((NN + 1) * 4);
    int* csrc   = (int*)alloc(EE * 4);

    k_prep<<<389, 256, 0, stream>>>(emb, d_in[4], d_in[5], d_in[6], d_in[7], d_in[8],
                                    d_in[9], d_in[10], d_in[11], d_in[12],
                                    x, ei, Wlf, blf, Wrf, WfT, hbw, gWf, linf,
                                    h0, eim, eimT, rowptr, csrc);
    k_sage0<<<256, 256, 0, stream>>>(ei, rowptr, csrc, h0, Wlf, blf, Wrf, h1, eim, eimT);
    k_sage1<<<256, 256, 0, stream>>>(rowptr, csrc, h1, Wlf, blf, Wrf, h2, hbf);
    k_bstage<<<2 * NN, 256, 0, stream>>>(h2, hbf, WfT, hbw, eim, eimT, vpp, vqp);
    k_ppqq2<<<2 * NN, DD, 0, stream>>>(vpp, vqp, gWf, ppb, qqb);
    k_final<<<PP / 64, 256, 0, stream>>>(emb, pos, hbf, gWf, eim, ppb, qqb, linf, d_out);
}

// Round 13
// 158.045 us; speedup vs baseline: 1.1014x; 1.0672x over previous
//
#include <hip/hip_runtime.h>
#include <hip/hip_bf16.h>

#define NN 1024
#define DD 64
#define EE 16384
#define PP 8192
#define EPSF 1e-5f
#define SWP (DD + 8)   // padded LDS row stride in shorts (144 B)

typedef __hip_bfloat16 bf16;
typedef __attribute__((ext_vector_type(8))) short short8;
typedef __attribute__((ext_vector_type(4))) float f32x4;

static __device__ __forceinline__ float dec1(const void* src, int i, int fl) {
    if (fl) return ((const float*)src)[i];
    return __bfloat162float(((const bf16*)src)[i]);
}
static __device__ __forceinline__ unsigned short f2bf_u(float f) {
    bf16 h = __float2bfloat16(f);
    return *reinterpret_cast<unsigned short*>(&h);
}
static __device__ __forceinline__ float bfu2f(unsigned short u) {
    return __uint_as_float(((unsigned int)u) << 16);
}
static __device__ __forceinline__ int probe_fl(const void* emb) {
    int lane = threadIdx.x & 63;
    unsigned short raw = ((const unsigned short*)emb)[lane];
    float v = __uint_as_float(((unsigned int)raw) << 16);
    return (__ballot(!(fabsf(v) <= 1e3f)) != 0ull) ? 1 : 0;
}

// =============== K1: decode + embed + zero bitmaps + fat-block CSR build ===============
// 98 blocks x 1024 threads. Blocks 0..96 carry 4 virtual 256-thread decode roles each
// (vb = b*4 + tid>>8). Block 97 = CSR build with 16 waves on one CU (R12 suspicion:
// the old 4-wave CSR block was the hidden ~40 us pole — latency-bound load->LDS-atomic
// rounds; 16 waves + 8-wide register batching give 128 outstanding wave-loads).
__global__ __launch_bounds__(1024) void k_prep(
        const void* __restrict__ emb, const void* __restrict__ sWl,
        const void* __restrict__ sbl, const void* __restrict__ sWr,
        const void* __restrict__ hW, const void* __restrict__ hb,
        const void* __restrict__ gW, const void* __restrict__ gb,
        const void* __restrict__ lW, const void* __restrict__ lb,
        const int* __restrict__ x, const int* __restrict__ ei,
        float* __restrict__ Wlf, float* __restrict__ blf, float* __restrict__ Wrf,
        float* __restrict__ WfT, float* __restrict__ hbw,
        float* __restrict__ gWf, float* __restrict__ linf,
        float* __restrict__ h0,
        unsigned int* __restrict__ eim, unsigned int* __restrict__ eimT,
        int* __restrict__ rowptr, int* __restrict__ csrc) {
    __shared__ int sdeg[NN];
    __shared__ int stmp[1024];
    const int b = blockIdx.x, tid = threadIdx.x;
    const int fl = probe_fl(emb);

    if (b < 97) {
        const int vb = b * 4 + (tid >> 8);
        const int vt = tid & 255;
        // zero the edge bitmaps (65536 words over vb 0..255)
        if (vb < 256) {
            int z = vb * 256 + vt;
            if (z < 32768) eim[z] = 0u;
            else           eimT[z - 32768] = 0u;
        }
        if (vb < 32) { int i = vb * 256 + vt; Wlf[i] = dec1(sWl, i, fl); }
        else if (vb == 32) { if (vt < 128) blf[vt] = dec1(sbl, vt, fl); }
        else if (vb < 65) { int i = (vb - 33) * 256 + vt; Wrf[i] = dec1(sWr, i, fl); }
        else if (vb < 82) {
            int i = (vb - 65) * 256 + vt;
            if (i < 4096) { int n = i >> 6, k = i & 63; WfT[n * DD + k] = dec1(hW, k * DD + n, fl); }
            else if (i < 4160) hbw[i - 4096] = dec1(hb, i - 4096, fl);
            else if (i < 4224) hbw[64 + (i - 4160)] = dec1(hW, 64 * DD + (i - 4160), fl);
        } else if (vb < 131) {
            int i = (vb - 82) * 256 + vt;
            if (i < 193 * DD) gWf[i] = dec1(gW, i, fl);
            else if (i < 194 * DD) gWf[i] = dec1(gb, i - 193 * DD, fl);
        } else if (vb == 131) {
            if (vt < DD) linf[vt] = dec1(lW, vt, fl);
            else if (vt == DD) linf[DD] = dec1(lb, 0, fl);
        } else if (vb < 388) {
            int i = (vb - 132) * 256 + vt;
            int node = i >> 6, f = i & 63;
            h0[i] = dec1(emb, x[node] * DD + f, fl);
        }
    } else {
        // ---- CSR build, 1024 threads (16 waves) ----
        sdeg[tid] = 0;
        __syncthreads();
        for (int base = 0; base < EE; base += 8192) {
            int d8[8];
#pragma unroll
            for (int u = 0; u < 8; ++u) d8[u] = ei[EE + base + u * 1024 + tid];
#pragma unroll
            for (int u = 0; u < 8; ++u) atomicAdd(&sdeg[d8[u]], 1);
        }
        __syncthreads();
        int v = sdeg[tid];
        stmp[tid] = v;
        __syncthreads();
        for (int off = 1; off < 1024; off <<= 1) {
            int a = (tid >= off) ? stmp[tid - off] : 0;
            __syncthreads();
            stmp[tid] += a;
            __syncthreads();
        }
        int excl = stmp[tid] - v;
        rowptr[tid] = excl;
        sdeg[tid] = excl;   // becomes cursor
        if (tid == 1023) rowptr[NN] = stmp[1023];
        __syncthreads();
        for (int base = 0; base < EE; base += 8192) {
            int d8[8], s8[8];
#pragma unroll
            for (int u = 0; u < 8; ++u) {
                d8[u] = ei[EE + base + u * 1024 + tid];
                s8[u] = ei[base + u * 1024 + tid];
            }
#pragma unroll
            for (int u = 0; u < 8; ++u) {
                int c = atomicAdd(&sdeg[d8[u]], 1);
                csrc[c] = s8[u];
            }
        }
    }
}

// =============== shared SAGE body (one wave per node) ===============
static __device__ __forceinline__ void sage_body(
        char* smem, int node, int lane, int wave,
        const int* __restrict__ rowptr, const int* __restrict__ csrc,
        const float* __restrict__ hin,
        const float* __restrict__ Wl, const float* __restrict__ bl,
        const float* __restrict__ Wr,
        float* __restrict__ hout, unsigned short* __restrict__ hbf) {
    float* sa = (float*)smem + wave * 2 * DD;
    float* sh = sa + DD;
    int r0 = rowptr[node], r1 = rowptr[node + 1];
    float s = 0.f;
    for (int r = r0; r < r1; ++r) s += hin[csrc[r] * DD + lane];
    sa[lane] = s / (float)max(r1 - r0, 1);
    sh[lane] = hin[node * DD + lane];
    float o = bl[lane];
    for (int k = 0; k < DD; ++k)
        o += sa[k] * Wl[k * DD + lane] + sh[k] * Wr[k * DD + lane];
    float m = o;
    for (int off = 32; off; off >>= 1) m += __shfl_xor(m, off);
    m *= (1.f / DD);
    float d0 = o - m;
    float v = d0 * d0;
    for (int off = 32; off; off >>= 1) v += __shfl_xor(v, off);
    v *= (1.f / DD);
    float r = d0 * rsqrtf(v + EPSF);
    hout[node * DD + lane] = r;
    if (hbf) hbf[node * DD + lane] = f2bf_u(r);
}

// =============== K2: SAGE round 0 + edge-bitmap atomics ===============
__global__ __launch_bounds__(256) void k_sage0(
        const int* __restrict__ ei,
        const int* __restrict__ rowptr, const int* __restrict__ csrc,
        const float* __restrict__ h0,
        const float* __restrict__ Wlf, const float* __restrict__ blf,
        const float* __restrict__ Wrf,
        float* __restrict__ h1,
        unsigned int* __restrict__ eim, unsigned int* __restrict__ eimT) {
    __shared__ __align__(16) char smem[4 * 2 * DD * 4];
    const int b = blockIdx.x, tid = threadIdx.x;
    const int lane = tid & 63, wave = tid >> 6;
    if (tid < 64) {
        int e = b * 64 + tid;
        int s = ei[e], d = ei[EE + e];
        unsigned int idx = (unsigned int)(s * NN + d);
        atomicOr(&eim[idx >> 5], 1u << (idx & 31));
        unsigned int idxT = (unsigned int)(d * NN + s);
        atomicOr(&eimT[idxT >> 5], 1u << (idxT & 31));
    }
    sage_body(smem, b * 4 + wave, lane, wave, rowptr, csrc, h0, Wlf, blf, Wrf,
              h1, (unsigned short*)nullptr);
}

// =============== K3: SAGE round 1 (writes h2 + bf16 copy) ===============
__global__ __launch_bounds__(256) void k_sage1(
        const int* __restrict__ rowptr, const int* __restrict__ csrc,
        const float* __restrict__ h1,
        const float* __restrict__ Wlf, const float* __restrict__ blf,
        const float* __restrict__ Wrf,
        float* __restrict__ h2, unsigned short* __restrict__ hbf) {
    __shared__ __align__(16) char smem[4 * 2 * DD * 4];
    const int b = blockIdx.x, tid = threadIdx.x;
    const int lane = tid & 63, wave = tid >> 6;
    sage_body(smem, b * 4 + wave, lane, wave, rowptr, csrc, h1,
              Wlf + DD * DD, blf + DD, Wrf + DD * DD, h2, hbf);
}

// =============== K4: B-stage (MFMA) + fused pp/qq projection (R10 verbatim — best measured) ===============
// NOTE: plain __launch_bounds__(256) — a (256,4) min-waves spec capped VGPR at 64
// and spilled ~100 live values to scratch (R8: WRITE 52 MB, FETCH 373 MB, 2.4x slower).
// R11 (ILP unroll-2) and R12 (grid 2048) both regressed vs this config; keep as-is.
__global__ __launch_bounds__(256) void k_bstage(
        const float* __restrict__ h2, const unsigned short* __restrict__ hbf,
        const float* __restrict__ WfT, const float* __restrict__ hbw,
        const unsigned int* __restrict__ eim, const unsigned int* __restrict__ eimT,
        const float* __restrict__ gWf,
        float* __restrict__ ppb, float* __restrict__ qqb) {
    __shared__ __align__(16) unsigned short sW[DD * SWP];  // 9216 B
    __shared__ __align__(16) float red[4 * 128];           // 2048 B
    const int b = blockIdx.x, tid = threadIdx.x;
    const int lane = tid & 63, wave = tid >> 6;
    const int l15 = lane & 15, quad = lane >> 4;

    {
        int m = tid >> 2;
        int k0 = (tid & 3) * 16;
        const float* hi = h2 + b * DD;
        const float* wr = WfT + m * DD;
        unsigned short tmp[16];
#pragma unroll
        for (int u = 0; u < 16; ++u) tmp[u] = f2bf_u(hi[k0 + u] * wr[k0 + u]);
        *(short8*)(sW + m * SWP + k0) = *(short8*)tmp;
        *(short8*)(sW + m * SWP + k0 + 8) = *(short8*)(tmp + 8);
    }
    __syncthreads();

    short8 Af[4][2];
#pragma unroll
    for (int mt = 0; mt < 4; ++mt)
#pragma unroll
        for (int kt = 0; kt < 2; ++kt)
            Af[mt][kt] = *(const short8*)(sW + (mt * 16 + l15) * SWP + kt * 32 + quad * 8);

    float hb0[4][4], hww[4][4];
#pragma unroll
    for (int mt = 0; mt < 4; ++mt) {
        f32x4 a = *(const f32x4*)(hbw + mt * 16 + quad * 4);
        f32x4 wv = *(const f32x4*)(hbw + 64 + mt * 16 + quad * 4);
#pragma unroll
        for (int r = 0; r < 4; ++r) { hb0[mt][r] = a[r]; hww[mt][r] = wv[r]; }
    }

    float accf[4][4], accb[4][4];
#pragma unroll
    for (int mt = 0; mt < 4; ++mt)
#pragma unroll
        for (int r = 0; r < 4; ++r) { accf[mt][r] = 0.f; accb[mt][r] = 0.f; }

    int g = wave;
    short8 B0 = *(const short8*)(hbf + (g * 16 + l15) * DD + quad * 8);
    short8 B1 = *(const short8*)(hbf + (g * 16 + l15) * DD + 32 + quad * 8);

    for (int it = 0; it < 16; ++it, g += 4) {
        short8 cB0 = B0, cB1 = B1;
        if (it < 15) {
            int gn = g + 4;
            B0 = *(const short8*)(hbf + (gn * 16 + l15) * DD + quad * 8);
            B1 = *(const short8*)(hbf + (gn * 16 + l15) * DD + 32 + quad * 8);
        }
        unsigned int base = (unsigned int)(b * NN + g * 16);
        unsigned int sf = (eim[base >> 5] >> (base & 31)) & 0xFFFFu;
        unsigned int sb = (eimT[base >> 5] >> (base & 31)) & 0xFFFFu;

        f32x4 C[4];
#pragma unroll
        for (int mt = 0; mt < 4; ++mt)
            C[mt] = (f32x4){hb0[mt][0], hb0[mt][1], hb0[mt][2], hb0[mt][3]};
#pragma unroll
        for (int mt = 0; mt < 4; ++mt)
            C[mt] = __builtin_amdgcn_mfma_f32_16x16x32_bf16(Af[mt][0], cB0, C[mt], 0, 0, 0);
#pragma unroll
        for (int mt = 0; mt < 4; ++mt)
            C[mt] = __builtin_amdgcn_mfma_f32_16x16x32_bf16(Af[mt][1], cB1, C[mt], 0, 0, 0);

        float ef = (float)((sf >> l15) & 1u);
        float s1 = 0.f, s2 = 0.f;
#pragma unroll
        for (int mt = 0; mt < 4; ++mt)
#pragma unroll
            for (int r = 0; r < 4; ++r) {
                float v = C[mt][r] + ef * hww[mt][r];
                C[mt][r] = v;
                s1 += v;
                s2 += v * v;
            }
        s1 += __shfl_xor(s1, 16); s1 += __shfl_xor(s1, 32);
        s2 += __shfl_xor(s2, 16); s2 += __shfl_xor(s2, 32);
        float mean = s1 * (1.f / DD);
        float var = fmaxf(s2 * (1.f / DD) - mean * mean, 0.f);
        float rs = rsqrtf(var + EPSF);
        float mrs = mean * rs;

        if (sf == sb) {
#pragma unroll
            for (int mt = 0; mt < 4; ++mt)
#pragma unroll
                for (int r = 0; r < 4; ++r) {
                    float u = fmaxf(C[mt][r] * rs - mrs, 0.f);
                    accf[mt][r] += u;
                    accb[mt][r] += u;
                }
        } else {
#pragma unroll
            for (int mt = 0; mt < 4; ++mt)
#pragma unroll
                for (int r = 0; r < 4; ++r)
                    accf[mt][r] += fmaxf(C[mt][r] * rs - mrs, 0.f);
            float de = (float)((sb >> l15) & 1u) - ef;
            float t1 = 0.f, t2 = 0.f;
#pragma unroll
            for (int mt = 0; mt < 4; ++mt)
#pragma unroll
                for (int r = 0; r < 4; ++r) {
                    float v = C[mt][r] + de * hww[mt][r];
                    C[mt][r] = v;
                    t1 += v;
                    t2 += v * v;
                }
            t1 += __shfl_xor(t1, 16); t1 += __shfl_xor(t1, 32);
            t2 += __shfl_xor(t2, 16); t2 += __shfl_xor(t2, 32);
            float mean2 = t1 * (1.f / DD);
            float var2 = fmaxf(t2 * (1.f / DD) - mean2 * mean2, 0.f);
            float rs2 = rsqrtf(var2 + EPSF);
            float mrs2 = mean2 * rs2;
#pragma unroll
            for (int mt = 0; mt < 4; ++mt)
#pragma unroll
                for (int r = 0; r < 4; ++r)
                    accb[mt][r] += fmaxf(C[mt][r] * rs2 - mrs2, 0.f);
        }
    }

#pragma unroll
    for (int step = 1; step < 16; step <<= 1)
#pragma unroll
        for (int mt = 0; mt < 4; ++mt)
#pragma unroll
            for (int r = 0; r < 4; ++r) {
                accf[mt][r] += __shfl_xor(accf[mt][r], step);
                accb[mt][r] += __shfl_xor(accb[mt][r], step);
            }
    if (l15 == 0) {
#pragma unroll
        for (int mt = 0; mt < 4; ++mt)
#pragma unroll
            for (int r = 0; r < 4; ++r) {
                int m = mt * 16 + quad * 4 + r;
                red[wave * 128 + m] = accf[mt][r];
                red[wave * 128 + DD + m] = accb[mt][r];
            }
    }
    __syncthreads();
    if (tid < 128) {
        float sum = red[tid] + red[128 + tid] + red[256 + tid] + red[384 + tid];
        red[tid] = sum;
    }
    __syncthreads();
    if (wave < 2) {
        const float* sv = red + wave * DD;
        int row0 = wave ? 129 : 65;
        float o = 0.f;
        for (int k = 0; k < DD; ++k) o += sv[k] * gWf[(row0 + k) * DD + lane];
        (wave ? qqb : ppb)[b * DD + lane] = o;
    }
}

// =============== K5: final selected pairs (MFMA, R10 verbatim) ===============
__global__ __launch_bounds__(256) void k_final(
        const void* __restrict__ emb,
        const int* __restrict__ pos, const unsigned short* __restrict__ hbf,
        const float* __restrict__ gWf, const unsigned int* __restrict__ eim,
        const float* __restrict__ ppb, const float* __restrict__ qqb,
        const float* __restrict__ linf, void* __restrict__ outv) {
    __shared__ __align__(16) unsigned short sgW[DD * SWP];
    const int b = blockIdx.x, tid = threadIdx.x;
    const int lane = tid & 63, wave = tid >> 6;
    const int l15 = lane & 15, quad = lane >> 4;
    const int fl = probe_fl(emb);

    {
        int m = tid >> 2;
        int k0 = (tid & 3) * 16;
        unsigned short tmp[16];
#pragma unroll
        for (int u = 0; u < 16; ++u) tmp[u] = f2bf_u(gWf[(k0 + u) * DD + m]);
        *(short8*)(sgW + m * SWP + k0) = *(short8*)tmp;
        *(short8*)(sgW + m * SWP + k0 + 8) = *(short8*)(tmp + 8);
    }

    int pp_ = b * 64 + wave * 16 + l15;
    int a = pos[2 * pp_], bb = pos[2 * pp_ + 1];
    short8 ha0 = *(const short8*)(hbf + a * DD + quad * 8);
    short8 hb0v = *(const short8*)(hbf + bb * DD + quad * 8);
    short8 ha1 = *(const short8*)(hbf + a * DD + 32 + quad * 8);
    short8 hb1v = *(const short8*)(hbf + bb * DD + 32 + quad * 8);
    short8 B0, B1;
#pragma unroll
    for (int j = 0; j < 8; ++j) {
        B0[j] = (short)f2bf_u(bfu2f((unsigned short)ha0[j]) * bfu2f((unsigned short)hb0v[j]));
        B1[j] = (short)f2bf_u(bfu2f((unsigned short)ha1[j]) * bfu2f((unsigned short)hb1v[j]));
    }
    __syncthreads();

    f32x4 C[4];
#pragma unroll
    for (int mt = 0; mt < 4; ++mt) C[mt] = (f32x4){0.f, 0.f, 0.f, 0.f};
#pragma unroll
    for (int mt = 0; mt < 4; ++mt) {
        short8 A0 = *(const short8*)(sgW + (mt * 16 + l15) * SWP + quad * 8);
        C[mt] = __builtin_amdgcn_mfma_f32_16x16x32_bf16(A0, B0, C[mt], 0, 0, 0);
    }
#pragma unroll
    for (int mt = 0; mt < 4; ++mt) {
        short8 A1 = *(const short8*)(sgW + (mt * 16 + l15) * SWP + 32 + quad * 8);
        C[mt] = __builtin_amdgcn_mfma_f32_16x16x32_bf16(A1, B1, C[mt], 0, 0, 0);
    }

    unsigned int iab = (unsigned int)(a * NN + bb), iba = (unsigned int)(bb * NN + a);
    float eab = (float)((eim[iab >> 5] >> (iab & 31)) & 1u);
    float eba = (float)((eim[iba >> 5] >> (iba & 31)) & 1u);

    float u1[4][4], u2[4][4];
    float s1 = 0.f, s12 = 0.f, s2 = 0.f, s22 = 0.f;
#pragma unroll
    for (int mt = 0; mt < 4; ++mt) {
        int m0 = mt * 16 + quad * 4;
        f32x4 w64v = *(const f32x4*)(gWf + 64 * DD + m0);
        f32x4 gbv  = *(const f32x4*)(gWf + 193 * DD + m0);
        f32x4 ppa  = *(const f32x4*)(ppb + a * DD + m0);
        f32x4 qqb_ = *(const f32x4*)(qqb + bb * DD + m0);
        f32x4 ppb_ = *(const f32x4*)(ppb + bb * DD + m0);
        f32x4 qqa  = *(const f32x4*)(qqb + a * DD + m0);
#pragma unroll
        for (int r = 0; r < 4; ++r) {
            float v1 = C[mt][r] + eab * w64v[r] + ppa[r] + qqb_[r] + gbv[r];
            float v2 = C[mt][r] + eba * w64v[r] + ppb_[r] + qqa[r] + gbv[r];
            u1[mt][r] = v1; u2[mt][r] = v2;
            s1 += v1; s12 += v1 * v1;
            s2 += v2; s22 += v2 * v2;
        }
    }
    s1 += __shfl_xor(s1, 16);  s1 += __shfl_xor(s1, 32);
    s12 += __shfl_xor(s12, 16); s12 += __shfl_xor(s12, 32);
    s2 += __shfl_xor(s2, 16);  s2 += __shfl_xor(s2, 32);
    s22 += __shfl_xor(s22, 16); s22 += __shfl_xor(s22, 32);
    float mean1 = s1 * (1.f / DD);
    float rs1 = rsqrtf(fmaxf(s12 * (1.f / DD) - mean1 * mean1, 0.f) + EPSF);
    float mrs1 = mean1 * rs1;
    float mean2 = s2 * (1.f / DD);
    float rs2 = rsqrtf(fmaxf(s22 * (1.f / DD) - mean2 * mean2, 0.f) + EPSF);
    float mrs2 = mean2 * rs2;

    float r = 0.f;
#pragma unroll
    for (int mt = 0; mt < 4; ++mt) {
        f32x4 lw = *(const f32x4*)(linf + mt * 16 + quad * 4);
#pragma unroll
        for (int rr = 0; rr < 4; ++rr) {
            float g1 = fmaxf(u1[mt][rr] * rs1 - mrs1, 0.f);
            float g2 = fmaxf(u2[mt][rr] * rs2 - mrs2, 0.f);
            r += g1 * g2 * lw[rr];
        }
    }
    r += __shfl_xor(r, 16); r += __shfl_xor(r, 32);
    if (quad == 0) {
        float res = r + linf[DD];
        if (fl) ((float*)outv)[pp_] = res;
        else    ((bf16*)outv)[pp_] = __float2bfloat16(res);
    }
}

extern "C" void kernel_launch(void* const* d_in, const int* in_sizes, int n_in,
                              void* d_out, int out_size, void* d_ws, size_t ws_size,
                              hipStream_t stream) {
    const int* x   = (const int*)d_in[0];
    const int* ei  = (const int*)d_in[1];
    const int* pos = (const int*)d_in[2];
    const void* emb = d_in[3];

    char* w = (char*)d_ws;
    auto alloc = [&](size_t bytes) {
        void* q = (void*)w;
        w += (bytes + 255) & ~(size_t)255;
        return q;
    };
    unsigned int* eim  = (unsigned int*)alloc(NN * NN / 8);
    unsigned int* eimT = (unsigned int*)alloc(NN * NN / 8);
    float* h0   = (float*)alloc(NN * DD * 4);
    float* h1   = (float*)alloc(NN * DD * 4);
    float* h2   = (float*)alloc(NN * DD * 4);
    unsigned short* hbf = (unsigned short*)alloc(NN * DD * 2);
    float* Wlf  = (float*)alloc(2 * DD * DD * 4);
    float* blf  = (float*)alloc(2 * DD * 4);
    float* Wrf  = (float*)alloc(2 * DD * DD * 4);
    float* WfT  = (float*)alloc(DD * DD * 4);
    float* hbw  = (float*)alloc(128 * 4);
    float* gWf  = (float*)alloc(194 * DD * 4);
    float* linf = (float*)alloc(65 * 4);
    float* ppb  = (float*)alloc(NN * DD * 4);
    float* qqb  = (float*)alloc(NN * DD * 4);
    int* rowptr = (int*)alloc((NN + 1) * 4);
    int* csrc   = (int*)alloc(EE * 4);

    k_prep<<<98, 1024, 0, stream>>>(emb, d_in[4], d_in[5], d_in[6], d_in[7], d_in[8],
                                    d_in[9], d_in[10], d_in[11], d_in[12],
                                    x, ei, Wlf, blf, Wrf, WfT, hbw, gWf, linf,
                                    h0, eim, eimT, rowptr, csrc);
    k_sage0<<<256, 256, 0, stream>>>(ei, rowptr, csrc, h0, Wlf, blf, Wrf, h1, eim, eimT);
    k_sage1<<<256, 256, 0, stream>>>(rowptr, csrc, h1, Wlf, blf, Wrf, h2, hbf);
    k_bstage<<<NN, 256, 0, stream>>>(h2, hbf, WfT, hbw, eim, eimT, gWf, ppb, qqb);
    k_final<<<PP / 64, 256, 0, stream>>>(emb, pos, hbf, gWf, eim, ppb, qqb, linf, d_out);
}

// Round 14
// 147.090 us; speedup vs baseline: 1.1835x; 1.0745x over previous
//
#include <hip/hip_runtime.h>
#include <hip/hip_bf16.h>

#define NN 1024
#define DD 64
#define EE 16384
#define PP 8192
#define EPSF 1e-5f
#define SWP (DD + 8)   // padded LDS row stride in shorts (144 B)

typedef __hip_bfloat16 bf16;
typedef __attribute__((ext_vector_type(8))) short short8;
typedef __attribute__((ext_vector_type(4))) float f32x4;
typedef __attribute__((ext_vector_type(2))) float f32x2;

static __device__ __forceinline__ float dec1(const void* src, int i, int fl) {
    if (fl) return ((const float*)src)[i];
    return __bfloat162float(((const bf16*)src)[i]);
}
static __device__ __forceinline__ unsigned short f2bf_u(float f) {
    bf16 h = __float2bfloat16(f);
    return *reinterpret_cast<unsigned short*>(&h);
}
static __device__ __forceinline__ float bfu2f(unsigned short u) {
    return __uint_as_float(((unsigned int)u) << 16);
}
static __device__ __forceinline__ int probe_fl(const void* emb) {
    int lane = threadIdx.x & 63;
    unsigned short raw = ((const unsigned short*)emb)[lane];
    float v = __uint_as_float(((unsigned int)raw) << 16);
    return (__ballot(!(fabsf(v) <= 1e3f)) != 0ull) ? 1 : 0;
}

// =============== K1: decode + embed + zero bitmaps + fat-block CSR (R13 verbatim) ===============
__global__ __launch_bounds__(1024) void k_prep(
        const void* __restrict__ emb, const void* __restrict__ sWl,
        const void* __restrict__ sbl, const void* __restrict__ sWr,
        const void* __restrict__ hW, const void* __restrict__ hb,
        const void* __restrict__ gW, const void* __restrict__ gb,
        const void* __restrict__ lW, const void* __restrict__ lb,
        const int* __restrict__ x, const int* __restrict__ ei,
        float* __restrict__ Wlf, float* __restrict__ blf, float* __restrict__ Wrf,
        float* __restrict__ WfT, float* __restrict__ hbw,
        float* __restrict__ gWf, float* __restrict__ linf,
        float* __restrict__ h0,
        unsigned int* __restrict__ eim, unsigned int* __restrict__ eimT,
        int* __restrict__ rowptr, int* __restrict__ csrc) {
    __shared__ int sdeg[NN];
    __shared__ int stmp[1024];
    const int b = blockIdx.x, tid = threadIdx.x;
    const int fl = probe_fl(emb);

    if (b < 97) {
        const int vb = b * 4 + (tid >> 8);
        const int vt = tid & 255;
        if (vb < 256) {
            int z = vb * 256 + vt;
            if (z < 32768) eim[z] = 0u;
            else           eimT[z - 32768] = 0u;
        }
        if (vb < 32) { int i = vb * 256 + vt; Wlf[i] = dec1(sWl, i, fl); }
        else if (vb == 32) { if (vt < 128) blf[vt] = dec1(sbl, vt, fl); }
        else if (vb < 65) { int i = (vb - 33) * 256 + vt; Wrf[i] = dec1(sWr, i, fl); }
        else if (vb < 82) {
            int i = (vb - 65) * 256 + vt;
            if (i < 4096) { int n = i >> 6, k = i & 63; WfT[n * DD + k] = dec1(hW, k * DD + n, fl); }
            else if (i < 4160) hbw[i - 4096] = dec1(hb, i - 4096, fl);
            else if (i < 4224) hbw[64 + (i - 4160)] = dec1(hW, 64 * DD + (i - 4160), fl);
        } else if (vb < 131) {
            int i = (vb - 82) * 256 + vt;
            if (i < 193 * DD) gWf[i] = dec1(gW, i, fl);
            else if (i < 194 * DD) gWf[i] = dec1(gb, i - 193 * DD, fl);
        } else if (vb == 131) {
            if (vt < DD) linf[vt] = dec1(lW, vt, fl);
            else if (vt == DD) linf[DD] = dec1(lb, 0, fl);
        } else if (vb < 388) {
            int i = (vb - 132) * 256 + vt;
            int node = i >> 6, f = i & 63;
            h0[i] = dec1(emb, x[node] * DD + f, fl);
        }
    } else {
        sdeg[tid] = 0;
        __syncthreads();
        for (int base = 0; base < EE; base += 8192) {
            int d8[8];
#pragma unroll
            for (int u = 0; u < 8; ++u) d8[u] = ei[EE + base + u * 1024 + tid];
#pragma unroll
            for (int u = 0; u < 8; ++u) atomicAdd(&sdeg[d8[u]], 1);
        }
        __syncthreads();
        int v = sdeg[tid];
        stmp[tid] = v;
        __syncthreads();
        for (int off = 1; off < 1024; off <<= 1) {
            int a = (tid >= off) ? stmp[tid - off] : 0;
            __syncthreads();
            stmp[tid] += a;
            __syncthreads();
        }
        int excl = stmp[tid] - v;
        rowptr[tid] = excl;
        sdeg[tid] = excl;
        if (tid == 1023) rowptr[NN] = stmp[1023];
        __syncthreads();
        for (int base = 0; base < EE; base += 8192) {
            int d8[8], s8[8];
#pragma unroll
            for (int u = 0; u < 8; ++u) {
                d8[u] = ei[EE + base + u * 1024 + tid];
                s8[u] = ei[base + u * 1024 + tid];
            }
#pragma unroll
            for (int u = 0; u < 8; ++u) {
                int c = atomicAdd(&sdeg[d8[u]], 1);
                csrc[c] = s8[u];
            }
        }
    }
}

// =============== SAGE body with LDS-staged weights ===============
static __device__ __forceinline__ void sage_core(
        const float* sWl, const float* sWr, float* sa, float* sh,
        int node, int lane,
        const int* __restrict__ rowptr, const int* __restrict__ csrc,
        const float* __restrict__ hin, const void* __restrict__ sbl, int boff, int fl,
        float* __restrict__ hout, unsigned short* __restrict__ hbf) {
    int r0 = rowptr[node], r1 = rowptr[node + 1];
    float s = 0.f;
    int r = r0;
    for (; r + 4 <= r1; r += 4) {
        int i0 = csrc[r], i1 = csrc[r + 1], i2 = csrc[r + 2], i3 = csrc[r + 3];
        float v0 = hin[i0 * DD + lane], v1 = hin[i1 * DD + lane];
        float v2 = hin[i2 * DD + lane], v3 = hin[i3 * DD + lane];
        s += (v0 + v1) + (v2 + v3);
    }
    for (; r < r1; ++r) s += hin[csrc[r] * DD + lane];
    sa[lane] = s / (float)max(r1 - r0, 1);
    sh[lane] = hin[node * DD + lane];
    float o = dec1(sbl, boff + lane, fl);
    for (int k = 0; k < DD; ++k)
        o += sa[k] * sWl[k * DD + lane] + sh[k] * sWr[k * DD + lane];
    float m = o;
    for (int off = 32; off; off >>= 1) m += __shfl_xor(m, off);
    m *= (1.f / DD);
    float d0 = o - m;
    float v = d0 * d0;
    for (int off = 32; off; off >>= 1) v += __shfl_xor(v, off);
    v *= (1.f / DD);
    float rr = d0 * rsqrtf(v + EPSF);
    hout[node * DD + lane] = rr;
    if (hbf) hbf[node * DD + lane] = f2bf_u(rr);
}

// =============== K2: SAGE round 0 + edge-bitmap atomics ===============
__global__ __launch_bounds__(256) void k_sage0(
        const void* __restrict__ emb, const int* __restrict__ ei,
        const int* __restrict__ rowptr, const int* __restrict__ csrc,
        const float* __restrict__ h0,
        const float* __restrict__ Wlf, const void* __restrict__ sbl,
        const float* __restrict__ Wrf,
        float* __restrict__ h1,
        unsigned int* __restrict__ eim, unsigned int* __restrict__ eimT) {
    __shared__ __align__(16) float sWl[DD * DD];
    __shared__ __align__(16) float sWr[DD * DD];
    __shared__ float sa4[4 * DD], sh4[4 * DD];
    const int b = blockIdx.x, tid = threadIdx.x;
    const int lane = tid & 63, wave = tid >> 6;
    const int fl = probe_fl(emb);
    for (int i = tid * 4; i < DD * DD; i += 1024) {
        *(float4*)(sWl + i) = *(const float4*)(Wlf + i);
        *(float4*)(sWr + i) = *(const float4*)(Wrf + i);
    }
    if (tid < 64) {
        int e = b * 64 + tid;
        int s = ei[e], d = ei[EE + e];
        unsigned int idx = (unsigned int)(s * NN + d);
        atomicOr(&eim[idx >> 5], 1u << (idx & 31));
        unsigned int idxT = (unsigned int)(d * NN + s);
        atomicOr(&eimT[idxT >> 5], 1u << (idxT & 31));
    }
    __syncthreads();
    sage_core(sWl, sWr, sa4 + wave * DD, sh4 + wave * DD, b * 4 + wave, lane,
              rowptr, csrc, h0, sbl, 0, fl, h1, (unsigned short*)nullptr);
}

// =============== K3: SAGE round 1 ===============
__global__ __launch_bounds__(256) void k_sage1(
        const void* __restrict__ emb,
        const int* __restrict__ rowptr, const int* __restrict__ csrc,
        const float* __restrict__ h1,
        const float* __restrict__ Wlf, const void* __restrict__ sbl,
        const float* __restrict__ Wrf,
        float* __restrict__ h2, unsigned short* __restrict__ hbf) {
    __shared__ __align__(16) float sWl[DD * DD];
    __shared__ __align__(16) float sWr[DD * DD];
    __shared__ float sa4[4 * DD], sh4[4 * DD];
    const int b = blockIdx.x, tid = threadIdx.x;
    const int lane = tid & 63, wave = tid >> 6;
    const int fl = probe_fl(emb);
    for (int i = tid * 4; i < DD * DD; i += 1024) {
        *(float4*)(sWl + i) = *(const float4*)(Wlf + DD * DD + i);
        *(float4*)(sWr + i) = *(const float4*)(Wrf + DD * DD + i);
    }
    __syncthreads();
    sage_core(sWl, sWr, sa4 + wave * DD, sh4 + wave * DD, b * 4 + wave, lane,
              rowptr, csrc, h1, sbl, DD, fl, h2, hbf);
}

// =============== packed-f32 LN epilogue ===============
static __device__ __forceinline__ void tile_ln_pk(
        const f32x4* C, unsigned int sf, unsigned int sb, int l15,
        const f32x2 hww2[4][2], f32x2 accf[4][2], f32x2 accb[4][2]) {
    float ef = (float)((sf >> l15) & 1u);
    f32x2 efv = {ef, ef};
    f32x2 s1v = {0.f, 0.f}, s2v = {0.f, 0.f};
    f32x2 V[4][2];
#pragma unroll
    for (int mt = 0; mt < 4; ++mt)
#pragma unroll
        for (int h = 0; h < 2; ++h) {
            f32x2 c = {C[mt][2 * h], C[mt][2 * h + 1]};   // C preloaded with hb0
            f32x2 v = c + efv * hww2[mt][h];
            V[mt][h] = v;
            s1v += v;
            s2v += v * v;
        }
    float s1 = s1v.x + s1v.y, s2 = s2v.x + s2v.y;
    s1 += __shfl_xor(s1, 16); s1 += __shfl_xor(s1, 32);
    s2 += __shfl_xor(s2, 16); s2 += __shfl_xor(s2, 32);
    float mean = s1 * (1.f / DD);
    float var = fmaxf(s2 * (1.f / DD) - mean * mean, 0.f);
    float rs = rsqrtf(var + EPSF);
    float mrs = mean * rs;
    f32x2 rsv = {rs, rs}, mrsv = {mrs, mrs}, zero = {0.f, 0.f};

    if (sf == sb) {
#pragma unroll
        for (int mt = 0; mt < 4; ++mt)
#pragma unroll
            for (int h = 0; h < 2; ++h) {
                f32x2 u = __builtin_elementwise_max(V[mt][h] * rsv - mrsv, zero);
                accf[mt][h] += u;
                accb[mt][h] += u;
            }
    } else {
#pragma unroll
        for (int mt = 0; mt < 4; ++mt)
#pragma unroll
            for (int h = 0; h < 2; ++h)
                accf[mt][h] += __builtin_elementwise_max(V[mt][h] * rsv - mrsv, zero);
        float de = (float)((sb >> l15) & 1u) - ef;
        f32x2 dev = {de, de};
        f32x2 t1v = {0.f, 0.f}, t2v = {0.f, 0.f};
#pragma unroll
        for (int mt = 0; mt < 4; ++mt)
#pragma unroll
            for (int h = 0; h < 2; ++h) {
                f32x2 v = V[mt][h] + dev * hww2[mt][h];
                V[mt][h] = v;
                t1v += v;
                t2v += v * v;
            }
        float t1 = t1v.x + t1v.y, t2 = t2v.x + t2v.y;
        t1 += __shfl_xor(t1, 16); t1 += __shfl_xor(t1, 32);
        t2 += __shfl_xor(t2, 16); t2 += __shfl_xor(t2, 32);
        float mean2 = t1 * (1.f / DD);
        float var2 = fmaxf(t2 * (1.f / DD) - mean2 * mean2, 0.f);
        float rs2 = rsqrtf(var2 + EPSF);
        float mrs2 = mean2 * rs2;
        f32x2 rs2v = {rs2, rs2}, mrs2v = {mrs2, mrs2};
#pragma unroll
        for (int mt = 0; mt < 4; ++mt)
#pragma unroll
            for (int h = 0; h < 2; ++h)
                accb[mt][h] += __builtin_elementwise_max(V[mt][h] * rs2v - mrs2v, zero);
    }
}

// =============== K4: B-stage (MFMA) + fused pp/qq (R10 structure, packed epilogue) ===============
// NOTE: plain __launch_bounds__(256) — (256,4) capped VGPR at 64 and spilled (R8).
__global__ __launch_bounds__(256) void k_bstage(
        const float* __restrict__ h2, const unsigned short* __restrict__ hbf,
        const float* __restrict__ WfT, const float* __restrict__ hbw,
        const unsigned int* __restrict__ eim, const unsigned int* __restrict__ eimT,
        const float* __restrict__ gWf,
        float* __restrict__ ppb, float* __restrict__ qqb) {
    __shared__ __align__(16) unsigned short sW[DD * SWP];  // 9216 B
    __shared__ __align__(16) float red[4 * 128];           // 2048 B
    const int b = blockIdx.x, tid = threadIdx.x;
    const int lane = tid & 63, wave = tid >> 6;
    const int l15 = lane & 15, quad = lane >> 4;

    {
        int m = tid >> 2;
        int k0 = (tid & 3) * 16;
        const float* hi = h2 + b * DD;
        const float* wr = WfT + m * DD;
        unsigned short tmp[16];
#pragma unroll
        for (int u = 0; u < 16; ++u) tmp[u] = f2bf_u(hi[k0 + u] * wr[k0 + u]);
        *(short8*)(sW + m * SWP + k0) = *(short8*)tmp;
        *(short8*)(sW + m * SWP + k0 + 8) = *(short8*)(tmp + 8);
    }
    __syncthreads();

    short8 Af[4][2];
#pragma unroll
    for (int mt = 0; mt < 4; ++mt)
#pragma unroll
        for (int kt = 0; kt < 2; ++kt)
            Af[mt][kt] = *(const short8*)(sW + (mt * 16 + l15) * SWP + kt * 32 + quad * 8);

    float hb0[4][4];
    f32x2 hww2[4][2];
#pragma unroll
    for (int mt = 0; mt < 4; ++mt) {
        f32x4 a = *(const f32x4*)(hbw + mt * 16 + quad * 4);
        f32x4 wv = *(const f32x4*)(hbw + 64 + mt * 16 + quad * 4);
#pragma unroll
        for (int r = 0; r < 4; ++r) hb0[mt][r] = a[r];
        hww2[mt][0] = (f32x2){wv[0], wv[1]};
        hww2[mt][1] = (f32x2){wv[2], wv[3]};
    }

    f32x2 accf[4][2], accb[4][2];
#pragma unroll
    for (int mt = 0; mt < 4; ++mt)
#pragma unroll
        for (int h = 0; h < 2; ++h) {
            accf[mt][h] = (f32x2){0.f, 0.f};
            accb[mt][h] = (f32x2){0.f, 0.f};
        }

    int g = wave;
    short8 B0 = *(const short8*)(hbf + (g * 16 + l15) * DD + quad * 8);
    short8 B1 = *(const short8*)(hbf + (g * 16 + l15) * DD + 32 + quad * 8);

    for (int it = 0; it < 16; ++it, g += 4) {
        short8 cB0 = B0, cB1 = B1;
        if (it < 15) {
            int gn = g + 4;
            B0 = *(const short8*)(hbf + (gn * 16 + l15) * DD + quad * 8);
            B1 = *(const short8*)(hbf + (gn * 16 + l15) * DD + 32 + quad * 8);
        }
        unsigned int base = (unsigned int)(b * NN + g * 16);
        unsigned int sf = (eim[base >> 5] >> (base & 31)) & 0xFFFFu;
        unsigned int sb = (eimT[base >> 5] >> (base & 31)) & 0xFFFFu;

        f32x4 C[4];
#pragma unroll
        for (int mt = 0; mt < 4; ++mt)
            C[mt] = (f32x4){hb0[mt][0], hb0[mt][1], hb0[mt][2], hb0[mt][3]};
#pragma unroll
        for (int mt = 0; mt < 4; ++mt)
            C[mt] = __builtin_amdgcn_mfma_f32_16x16x32_bf16(Af[mt][0], cB0, C[mt], 0, 0, 0);
#pragma unroll
        for (int mt = 0; mt < 4; ++mt)
            C[mt] = __builtin_amdgcn_mfma_f32_16x16x32_bf16(Af[mt][1], cB1, C[mt], 0, 0, 0);

        tile_ln_pk(C, sf, sb, l15, hww2, accf, accb);
    }

    // unpack to scalar for the cross-lane reduce
    float af[4][4], ab[4][4];
#pragma unroll
    for (int mt = 0; mt < 4; ++mt)
#pragma unroll
        for (int h = 0; h < 2; ++h) {
            af[mt][2 * h] = accf[mt][h].x;  af[mt][2 * h + 1] = accf[mt][h].y;
            ab[mt][2 * h] = accb[mt][h].x;  ab[mt][2 * h + 1] = accb[mt][h].y;
        }
#pragma unroll
    for (int step = 1; step < 16; step <<= 1)
#pragma unroll
        for (int mt = 0; mt < 4; ++mt)
#pragma unroll
            for (int r = 0; r < 4; ++r) {
                af[mt][r] += __shfl_xor(af[mt][r], step);
                ab[mt][r] += __shfl_xor(ab[mt][r], step);
            }
    if (l15 == 0) {
#pragma unroll
        for (int mt = 0; mt < 4; ++mt)
#pragma unroll
            for (int r = 0; r < 4; ++r) {
                int m = mt * 16 + quad * 4 + r;
                red[wave * 128 + m] = af[mt][r];
                red[wave * 128 + DD + m] = ab[mt][r];
            }
    }
    __syncthreads();
    if (tid < 128) {
        float sum = red[tid] + red[128 + tid] + red[256 + tid] + red[384 + tid];
        red[tid] = sum;
    }
    __syncthreads();
    if (wave < 2) {
        const float* sv = red + wave * DD;
        int row0 = wave ? 129 : 65;
        float o = 0.f;
        for (int k = 0; k < DD; ++k) o += sv[k] * gWf[(row0 + k) * DD + lane];
        (wave ? qqb : ppb)[b * DD + lane] = o;
    }
}

// =============== K5: final selected pairs (MFMA) — 256 blocks x 128 threads ===============
__global__ __launch_bounds__(128) void k_final(
        const void* __restrict__ emb,
        const int* __restrict__ pos, const unsigned short* __restrict__ hbf,
        const float* __restrict__ gWf, const unsigned int* __restrict__ eim,
        const float* __restrict__ ppb, const float* __restrict__ qqb,
        const float* __restrict__ linf, void* __restrict__ outv) {
    __shared__ __align__(16) unsigned short sgW[DD * SWP];
    const int b = blockIdx.x, tid = threadIdx.x;
    const int lane = tid & 63, wave = tid >> 6;   // wave 0..1
    const int l15 = lane & 15, quad = lane >> 4;
    const int fl = probe_fl(emb);

    {
        int m = tid >> 1;
        int k0 = (tid & 1) * 32;
        unsigned short tmp[32];
#pragma unroll
        for (int u = 0; u < 32; ++u) tmp[u] = f2bf_u(gWf[(k0 + u) * DD + m]);
#pragma unroll
        for (int q = 0; q < 4; ++q)
            *(short8*)(sgW + m * SWP + k0 + q * 8) = *(short8*)(tmp + q * 8);
    }

    int pp_ = b * 32 + wave * 16 + l15;
    int a = pos[2 * pp_], bb = pos[2 * pp_ + 1];
    short8 ha0 = *(const short8*)(hbf + a * DD + quad * 8);
    short8 hb0v = *(const short8*)(hbf + bb * DD + quad * 8);
    short8 ha1 = *(const short8*)(hbf + a * DD + 32 + quad * 8);
    short8 hb1v = *(const short8*)(hbf + bb * DD + 32 + quad * 8);
    short8 B0, B1;
#pragma unroll
    for (int j = 0; j < 8; ++j) {
        B0[j] = (short)f2bf_u(bfu2f((unsigned short)ha0[j]) * bfu2f((unsigned short)hb0v[j]));
        B1[j] = (short)f2bf_u(bfu2f((unsigned short)ha1[j]) * bfu2f((unsigned short)hb1v[j]));
    }
    __syncthreads();

    f32x4 C[4];
#pragma unroll
    for (int mt = 0; mt < 4; ++mt) C[mt] = (f32x4){0.f, 0.f, 0.f, 0.f};
#pragma unroll
    for (int mt = 0; mt < 4; ++mt) {
        short8 A0 = *(const short8*)(sgW + (mt * 16 + l15) * SWP + quad * 8);
        C[mt] = __builtin_amdgcn_mfma_f32_16x16x32_bf16(A0, B0, C[mt], 0, 0, 0);
    }
#pragma unroll
    for (int mt = 0; mt < 4; ++mt) {
        short8 A1 = *(const short8*)(sgW + (mt * 16 + l15) * SWP + 32 + quad * 8);
        C[mt] = __builtin_amdgcn_mfma_f32_16x16x32_bf16(A1, B1, C[mt], 0, 0, 0);
    }

    unsigned int iab = (unsigned int)(a * NN + bb), iba = (unsigned int)(bb * NN + a);
    float eab = (float)((eim[iab >> 5] >> (iab & 31)) & 1u);
    float eba = (float)((eim[iba >> 5] >> (iba & 31)) & 1u);

    float u1[4][4], u2[4][4];
    float s1 = 0.f, s12 = 0.f, s2 = 0.f, s22 = 0.f;
#pragma unroll
    for (int mt = 0; mt < 4; ++mt) {
        int m0 = mt * 16 + quad * 4;
        f32x4 w64v = *(const f32x4*)(gWf + 64 * DD + m0);
        f32x4 gbv  = *(const f32x4*)(gWf + 193 * DD + m0);
        f32x4 ppa  = *(const f32x4*)(ppb + a * DD + m0);
        f32x4 qqb_ = *(const f32x4*)(qqb + bb * DD + m0);
        f32x4 ppb_ = *(const f32x4*)(ppb + bb * DD + m0);
        f32x4 qqa  = *(const f32x4*)(qqb + a * DD + m0);
#pragma unroll
        for (int r = 0; r < 4; ++r) {
            float v1 = C[mt][r] + eab * w64v[r] + ppa[r] + qqb_[r] + gbv[r];
            float v2 = C[mt][r] + eba * w64v[r] + ppb_[r] + qqa[r] + gbv[r];
            u1[mt][r] = v1; u2[mt][r] = v2;
            s1 += v1; s12 += v1 * v1;
            s2 += v2; s22 += v2 * v2;
        }
    }
    s1 += __shfl_xor(s1, 16);  s1 += __shfl_xor(s1, 32);
    s12 += __shfl_xor(s12, 16); s12 += __shfl_xor(s12, 32);
    s2 += __shfl_xor(s2, 16);  s2 += __shfl_xor(s2, 32);
    s22 += __shfl_xor(s22, 16); s22 += __shfl_xor(s22, 32);
    float mean1 = s1 * (1.f / DD);
    float rs1 = rsqrtf(fmaxf(s12 * (1.f / DD) - mean1 * mean1, 0.f) + EPSF);
    float mrs1 = mean1 * rs1;
    float mean2 = s2 * (1.f / DD);
    float rs2 = rsqrtf(fmaxf(s22 * (1.f / DD) - mean2 * mean2, 0.f) + EPSF);
    float mrs2 = mean2 * rs2;

    float r = 0.f;
#pragma unroll
    for (int mt = 0; mt < 4; ++mt) {
        f32x4 lw = *(const f32x4*)(linf + mt * 16 + quad * 4);
#pragma unroll
        for (int rr = 0; rr < 4; ++rr) {
            float g1 = fmaxf(u1[mt][rr] * rs1 - mrs1, 0.f);
            float g2 = fmaxf(u2[mt][rr] * rs2 - mrs2, 0.f);
            r += g1 * g2 * lw[rr];
        }
    }
    r += __shfl_xor(r, 16); r += __shfl_xor(r, 32);
    if (quad == 0) {
        float res = r + linf[DD];
        if (fl) ((float*)outv)[pp_] = res;
        else    ((bf16*)outv)[pp_] = __float2bfloat16(res);
    }
}

extern "C" void kernel_launch(void* const* d_in, const int* in_sizes, int n_in,
                              void* d_out, int out_size, void* d_ws, size_t ws_size,
                              hipStream_t stream) {
    const int* x   = (const int*)d_in[0];
    const int* ei  = (const int*)d_in[1];
    const int* pos = (const int*)d_in[2];
    const void* emb = d_in[3];

    char* w = (char*)d_ws;
    auto alloc = [&](size_t bytes) {
        void* q = (void*)w;
        w += (bytes + 255) & ~(size_t)255;
        return q;
    };
    unsigned int* eim  = (unsigned int*)alloc(NN * NN / 8);
    unsigned int* eimT = (unsigned int*)alloc(NN * NN / 8);
    float* h0   = (float*)alloc(NN * DD * 4);
    float* h1   = (float*)alloc(NN * DD * 4);
    float* h2   = (float*)alloc(NN * DD * 4);
    unsigned short* hbf = (unsigned short*)alloc(NN * DD * 2);
    float* Wlf  = (float*)alloc(2 * DD * DD * 4);
    float* blf  = (float*)alloc(2 * DD * 4);
    float* Wrf  = (float*)alloc(2 * DD * DD * 4);
    float* WfT  = (float*)alloc(DD * DD * 4);
    float* hbw  = (float*)alloc(128 * 4);
    float* gWf  = (float*)alloc(194 * DD * 4);
    float* linf = (float*)alloc(65 * 4);
    float* ppb  = (float*)alloc(NN * DD * 4);
    float* qqb  = (float*)alloc(NN * DD * 4);
    int* rowptr = (int*)alloc((NN + 1) * 4);
    int* csrc   = (int*)alloc(EE * 4);

    k_prep<<<98, 1024, 0, stream>>>(emb, d_in[4], d_in[5], d_in[6], d_in[7], d_in[8],
                                    d_in[9], d_in[10], d_in[11], d_in[12],
                                    x, ei, Wlf, blf, Wrf, WfT, hbw, gWf, linf,
                                    h0, eim, eimT, rowptr, csrc);
    k_sage0<<<256, 256, 0, stream>>>(emb, ei, rowptr, csrc, h0, Wlf, d_in[5], Wrf,
                                     h1, eim, eimT);
    k_sage1<<<256, 256, 0, stream>>>(emb, rowptr, csrc, h1, Wlf, d_in[5], Wrf, h2, hbf);
    k_bstage<<<NN, 256, 0, stream>>>(h2, hbf, WfT, hbw, eim, eimT, gWf, ppb, qqb);
    k_final<<<PP / 32, 128, 0, stream>>>(emb, pos, hbf, gWf, eim, ppb, qqb, linf, d_out);
}

// Round 15
// 146.804 us; speedup vs baseline: 1.1858x; 1.0020x over previous
//
#include <hip/hip_runtime.h>
#include <hip/hip_bf16.h>

#define NN 1024
#define DD 64
#define EE 16384
#define PP 8192
#define EPSF 1e-5f
#define SWP (DD + 8)   // padded LDS row stride in shorts (144 B)

typedef __hip_bfloat16 bf16;
typedef __attribute__((ext_vector_type(8))) short short8;
typedef __attribute__((ext_vector_type(4))) float f32x4;

static __device__ __forceinline__ float dec1(const void* src, int i, int fl) {
    if (fl) return ((const float*)src)[i];
    return __bfloat162float(((const bf16*)src)[i]);
}
static __device__ __forceinline__ unsigned short f2bf_u(float f) {
    bf16 h = __float2bfloat16(f);
    return *reinterpret_cast<unsigned short*>(&h);
}
static __device__ __forceinline__ float bfu2f(unsigned short u) {
    return __uint_as_float(((unsigned int)u) << 16);
}
static __device__ __forceinline__ int probe_fl(const void* emb) {
    int lane = threadIdx.x & 63;
    unsigned short raw = ((const unsigned short*)emb)[lane];
    float v = __uint_as_float(((unsigned int)raw) << 16);
    return (__ballot(!(fabsf(v) <= 1e3f)) != 0ull) ? 1 : 0;
}

// =============== K1: decode + embed + zero bitmaps + fat-block CSR (R13 verbatim) ===============
__global__ __launch_bounds__(1024) void k_prep(
        const void* __restrict__ emb, const void* __restrict__ sWl,
        const void* __restrict__ sbl, const void* __restrict__ sWr,
        const void* __restrict__ hW, const void* __restrict__ hb,
        const void* __restrict__ gW, const void* __restrict__ gb,
        const void* __restrict__ lW, const void* __restrict__ lb,
        const int* __restrict__ x, const int* __restrict__ ei,
        float* __restrict__ Wlf, float* __restrict__ blf, float* __restrict__ Wrf,
        float* __restrict__ WfT, float* __restrict__ hbw,
        float* __restrict__ gWf, float* __restrict__ linf,
        float* __restrict__ h0,
        unsigned int* __restrict__ eim, unsigned int* __restrict__ eimT,
        int* __restrict__ rowptr, int* __restrict__ csrc) {
    __shared__ int sdeg[NN];
    __shared__ int stmp[1024];
    const int b = blockIdx.x, tid = threadIdx.x;
    const int fl = probe_fl(emb);

    if (b < 97) {
        const int vb = b * 4 + (tid >> 8);
        const int vt = tid & 255;
        if (vb < 256) {
            int z = vb * 256 + vt;
            if (z < 32768) eim[z] = 0u;
            else           eimT[z - 32768] = 0u;
        }
        if (vb < 32) { int i = vb * 256 + vt; Wlf[i] = dec1(sWl, i, fl); }
        else if (vb == 32) { if (vt < 128) blf[vt] = dec1(sbl, vt, fl); }
        else if (vb < 65) { int i = (vb - 33) * 256 + vt; Wrf[i] = dec1(sWr, i, fl); }
        else if (vb < 82) {
            int i = (vb - 65) * 256 + vt;
            if (i < 4096) { int n = i >> 6, k = i & 63; WfT[n * DD + k] = dec1(hW, k * DD + n, fl); }
            else if (i < 4160) hbw[i - 4096] = dec1(hb, i - 4096, fl);
            else if (i < 4224) hbw[64 + (i - 4160)] = dec1(hW, 64 * DD + (i - 4160), fl);
        } else if (vb < 131) {
            int i = (vb - 82) * 256 + vt;
            if (i < 193 * DD) gWf[i] = dec1(gW, i, fl);
            else if (i < 194 * DD) gWf[i] = dec1(gb, i - 193 * DD, fl);
        } else if (vb == 131) {
            if (vt < DD) linf[vt] = dec1(lW, vt, fl);
            else if (vt == DD) linf[DD] = dec1(lb, 0, fl);
        } else if (vb < 388) {
            int i = (vb - 132) * 256 + vt;
            int node = i >> 6, f = i & 63;
            h0[i] = dec1(emb, x[node] * DD + f, fl);
        }
    } else {
        sdeg[tid] = 0;
        __syncthreads();
        for (int base = 0; base < EE; base += 8192) {
            int d8[8];
#pragma unroll
            for (int u = 0; u < 8; ++u) d8[u] = ei[EE + base + u * 1024 + tid];
#pragma unroll
            for (int u = 0; u < 8; ++u) atomicAdd(&sdeg[d8[u]], 1);
        }
        __syncthreads();
        int v = sdeg[tid];
        stmp[tid] = v;
        __syncthreads();
        for (int off = 1; off < 1024; off <<= 1) {
            int a = (tid >= off) ? stmp[tid - off] : 0;
            __syncthreads();
            stmp[tid] += a;
            __syncthreads();
        }
        int excl = stmp[tid] - v;
        rowptr[tid] = excl;
        sdeg[tid] = excl;
        if (tid == 1023) rowptr[NN] = stmp[1023];
        __syncthreads();
        for (int base = 0; base < EE; base += 8192) {
            int d8[8], s8[8];
#pragma unroll
            for (int u = 0; u < 8; ++u) {
                d8[u] = ei[EE + base + u * 1024 + tid];
                s8[u] = ei[base + u * 1024 + tid];
            }
#pragma unroll
            for (int u = 0; u < 8; ++u) {
                int c = atomicAdd(&sdeg[d8[u]], 1);
                csrc[c] = s8[u];
            }
        }
    }
}

// =============== SAGE body with LDS-staged weights (R14 verbatim) ===============
static __device__ __forceinline__ void sage_core(
        const float* sWl, const float* sWr, float* sa, float* sh,
        int node, int lane,
        const int* __restrict__ rowptr, const int* __restrict__ csrc,
        const float* __restrict__ hin, const void* __restrict__ sbl, int boff, int fl,
        float* __restrict__ hout, unsigned short* __restrict__ hbf) {
    int r0 = rowptr[node], r1 = rowptr[node + 1];
    float s = 0.f;
    int r = r0;
    for (; r + 4 <= r1; r += 4) {
        int i0 = csrc[r], i1 = csrc[r + 1], i2 = csrc[r + 2], i3 = csrc[r + 3];
        float v0 = hin[i0 * DD + lane], v1 = hin[i1 * DD + lane];
        float v2 = hin[i2 * DD + lane], v3 = hin[i3 * DD + lane];
        s += (v0 + v1) + (v2 + v3);
    }
    for (; r < r1; ++r) s += hin[csrc[r] * DD + lane];
    sa[lane] = s / (float)max(r1 - r0, 1);
    sh[lane] = hin[node * DD + lane];
    float o = dec1(sbl, boff + lane, fl);
    for (int k = 0; k < DD; ++k)
        o += sa[k] * sWl[k * DD + lane] + sh[k] * sWr[k * DD + lane];
    float m = o;
    for (int off = 32; off; off >>= 1) m += __shfl_xor(m, off);
    m *= (1.f / DD);
    float d0 = o - m;
    float v = d0 * d0;
    for (int off = 32; off; off >>= 1) v += __shfl_xor(v, off);
    v *= (1.f / DD);
    float rr = d0 * rsqrtf(v + EPSF);
    hout[node * DD + lane] = rr;
    if (hbf) hbf[node * DD + lane] = f2bf_u(rr);
}

// =============== K2: SAGE round 0 + edge-bitmap atomics ===============
__global__ __launch_bounds__(256) void k_sage0(
        const void* __restrict__ emb, const int* __restrict__ ei,
        const int* __restrict__ rowptr, const int* __restrict__ csrc,
        const float* __restrict__ h0,
        const float* __restrict__ Wlf, const void* __restrict__ sbl,
        const float* __restrict__ Wrf,
        float* __restrict__ h1,
        unsigned int* __restrict__ eim, unsigned int* __restrict__ eimT) {
    __shared__ __align__(16) float sWl[DD * DD];
    __shared__ __align__(16) float sWr[DD * DD];
    __shared__ float sa4[4 * DD], sh4[4 * DD];
    const int b = blockIdx.x, tid = threadIdx.x;
    const int lane = tid & 63, wave = tid >> 6;
    const int fl = probe_fl(emb);
    for (int i = tid * 4; i < DD * DD; i += 1024) {
        *(float4*)(sWl + i) = *(const float4*)(Wlf + i);
        *(float4*)(sWr + i) = *(const float4*)(Wrf + i);
    }
    if (tid < 64) {
        int e = b * 64 + tid;
        int s = ei[e], d = ei[EE + e];
        unsigned int idx = (unsigned int)(s * NN + d);
        atomicOr(&eim[idx >> 5], 1u << (idx & 31));
        unsigned int idxT = (unsigned int)(d * NN + s);
        atomicOr(&eimT[idxT >> 5], 1u << (idxT & 31));
    }
    __syncthreads();
    sage_core(sWl, sWr, sa4 + wave * DD, sh4 + wave * DD, b * 4 + wave, lane,
              rowptr, csrc, h0, sbl, 0, fl, h1, (unsigned short*)nullptr);
}

// =============== K3: SAGE round 1 ===============
__global__ __launch_bounds__(256) void k_sage1(
        const void* __restrict__ emb,
        const int* __restrict__ rowptr, const int* __restrict__ csrc,
        const float* __restrict__ h1,
        const float* __restrict__ Wlf, const void* __restrict__ sbl,
        const float* __restrict__ Wrf,
        float* __restrict__ h2, unsigned short* __restrict__ hbf) {
    __shared__ __align__(16) float sWl[DD * DD];
    __shared__ __align__(16) float sWr[DD * DD];
    __shared__ float sa4[4 * DD], sh4[4 * DD];
    const int b = blockIdx.x, tid = threadIdx.x;
    const int lane = tid & 63, wave = tid >> 6;
    const int fl = probe_fl(emb);
    for (int i = tid * 4; i < DD * DD; i += 1024) {
        *(float4*)(sWl + i) = *(const float4*)(Wlf + DD * DD + i);
        *(float4*)(sWr + i) = *(const float4*)(Wrf + DD * DD + i);
    }
    __syncthreads();
    sage_core(sWl, sWr, sa4 + wave * DD, sh4 + wave * DD, b * 4 + wave, lane,
              rowptr, csrc, h1, sbl, DD, fl, h2, hbf);
}

// =============== K4: B-stage (MFMA) + fused pp/qq — in-place f32x4 epilogue,
// running pointers, incremental mixed-tile stats ===============
// NOTE: plain __launch_bounds__(256) — (256,4) capped VGPR at 64 and spilled (R8).
__global__ __launch_bounds__(256) void k_bstage(
        const float* __restrict__ h2, const unsigned short* __restrict__ hbf,
        const float* __restrict__ WfT, const float* __restrict__ hbw,
        const unsigned int* __restrict__ eim, const unsigned int* __restrict__ eimT,
        const float* __restrict__ gWf,
        float* __restrict__ ppb, float* __restrict__ qqb) {
    __shared__ __align__(16) unsigned short sW[DD * SWP];  // 9216 B
    __shared__ __align__(16) float red[4 * 128];           // 2048 B
    __shared__ float swc[2];                               // {sum w64, sum w64^2}
    const int b = blockIdx.x, tid = threadIdx.x;
    const int lane = tid & 63, wave = tid >> 6;
    const int l15 = lane & 15, quad = lane >> 4;

    {
        int m = tid >> 2;
        int k0 = (tid & 3) * 16;
        const float* hi = h2 + b * DD;
        const float* wr = WfT + m * DD;
        unsigned short tmp[16];
#pragma unroll
        for (int u = 0; u < 16; ++u) tmp[u] = f2bf_u(hi[k0 + u] * wr[k0 + u]);
        *(short8*)(sW + m * SWP + k0) = *(short8*)tmp;
        *(short8*)(sW + m * SWP + k0 + 8) = *(short8*)(tmp + 8);
    }
    if (wave == 0) {   // block constants for incremental mixed-tile stats
        float wv = hbw[64 + lane];
        float s = wv, s2 = wv * wv;
        for (int off = 32; off; off >>= 1) {
            s += __shfl_xor(s, off);
            s2 += __shfl_xor(s2, off);
        }
        if (lane == 0) { swc[0] = s; swc[1] = s2; }
    }
    __syncthreads();
    const float SW = swc[0], SWW = swc[1];

    short8 Af[4][2];
#pragma unroll
    for (int mt = 0; mt < 4; ++mt)
#pragma unroll
        for (int kt = 0; kt < 2; ++kt)
            Af[mt][kt] = *(const short8*)(sW + (mt * 16 + l15) * SWP + kt * 32 + quad * 8);

    f32x4 hb04[4], hww4[4];
#pragma unroll
    for (int mt = 0; mt < 4; ++mt) {
        hb04[mt] = *(const f32x4*)(hbw + mt * 16 + quad * 4);
        hww4[mt] = *(const f32x4*)(hbw + 64 + mt * 16 + quad * 4);
    }

    f32x4 accf[4], accb[4];
#pragma unroll
    for (int mt = 0; mt < 4; ++mt) {
        accf[mt] = (f32x4){0.f, 0.f, 0.f, 0.f};
        accb[mt] = (f32x4){0.f, 0.f, 0.f, 0.f};
    }

    // running pointers: B rows advance by 4 groups * 16 rows * 64 shorts = 4096/iter;
    // eim words advance by 2/iter; bit shift is per-wave constant.
    const unsigned short* pB = hbf + (wave * 16 + l15) * DD + quad * 8;
    const unsigned int* pF = eim + b * 32 + (wave >> 1);
    const unsigned int* pBk = eimT + b * 32 + (wave >> 1);
    const int shft = (wave & 1) * 16;

    short8 B0 = *(const short8*)(pB);
    short8 B1 = *(const short8*)(pB + 32);
    pB += 4096;

    for (int it = 0; it < 16; ++it) {
        short8 cB0 = B0, cB1 = B1;
        B0 = *(const short8*)(pB);        // last-iter prefetch reads unused ws bytes (safe)
        B1 = *(const short8*)(pB + 32);
        pB += 4096;
        unsigned int sf = (pF[0] >> shft) & 0xFFFFu;
        unsigned int sb = (pBk[0] >> shft) & 0xFFFFu;
        pF += 2; pBk += 2;

        f32x4 C[4];
#pragma unroll
        for (int mt = 0; mt < 4; ++mt) C[mt] = hb04[mt];
#pragma unroll
        for (int mt = 0; mt < 4; ++mt)
            C[mt] = __builtin_amdgcn_mfma_f32_16x16x32_bf16(Af[mt][0], cB0, C[mt], 0, 0, 0);
#pragma unroll
        for (int mt = 0; mt < 4; ++mt)
            C[mt] = __builtin_amdgcn_mfma_f32_16x16x32_bf16(Af[mt][1], cB1, C[mt], 0, 0, 0);

        float ef = (float)((sf >> l15) & 1u);
        f32x4 efv = {ef, ef, ef, ef};
        f32x4 s1a = {0.f, 0.f, 0.f, 0.f}, s2a = {0.f, 0.f, 0.f, 0.f};
#pragma unroll
        for (int mt = 0; mt < 4; ++mt) {
            C[mt] += efv * hww4[mt];
            s1a += C[mt];
            s2a += C[mt] * C[mt];
        }
        float s1 = (s1a.x + s1a.y) + (s1a.z + s1a.w);
        float s2 = (s2a.x + s2a.y) + (s2a.z + s2a.w);
        s1 += __shfl_xor(s1, 16); s1 += __shfl_xor(s1, 32);
        s2 += __shfl_xor(s2, 16); s2 += __shfl_xor(s2, 32);
        float mean = s1 * (1.f / DD);
        float var = fmaxf(s2 * (1.f / DD) - mean * mean, 0.f);
        float rs = rsqrtf(var + EPSF);
        float mrs = mean * rs;
        f32x4 rsv = {rs, rs, rs, rs}, mrsv = {mrs, mrs, mrs, mrs};
        f32x4 zero = {0.f, 0.f, 0.f, 0.f};

        if (sf == sb) {
#pragma unroll
            for (int mt = 0; mt < 4; ++mt) {
                f32x4 u = __builtin_elementwise_max(C[mt] * rsv - mrsv, zero);
                accf[mt] += u;
                accb[mt] += u;
            }
        } else {
#pragma unroll
            for (int mt = 0; mt < 4; ++mt)
                accf[mt] += __builtin_elementwise_max(C[mt] * rsv - mrsv, zero);
            float de = (float)((sb >> l15) & 1u) - ef;
            // incremental stats: T2 = C + de*w64
            f32x4 dva = {0.f, 0.f, 0.f, 0.f};
#pragma unroll
            for (int mt = 0; mt < 4; ++mt) dva += C[mt] * hww4[mt];
            float dot = (dva.x + dva.y) + (dva.z + dva.w);
            dot += __shfl_xor(dot, 16); dot += __shfl_xor(dot, 32);
            float t1 = s1 + de * SW;
            float t2 = s2 + 2.f * de * dot + de * de * SWW;
            float mean2 = t1 * (1.f / DD);
            float var2 = fmaxf(t2 * (1.f / DD) - mean2 * mean2, 0.f);
            float rs2 = rsqrtf(var2 + EPSF);
            float mrs2 = mean2 * rs2;
            float drs = de * rs2;
            f32x4 rs2v = {rs2, rs2, rs2, rs2};
            f32x4 mrs2v = {mrs2, mrs2, mrs2, mrs2};
            f32x4 drsv = {drs, drs, drs, drs};
#pragma unroll
            for (int mt = 0; mt < 4; ++mt) {
                f32x4 th = mrs2v - drsv * hww4[mt];  // T2*rs2 - mrs2 == C*rs2 - th
                accb[mt] += __builtin_elementwise_max(C[mt] * rs2v - th, zero);
            }
        }
    }

    float af[4][4], ab[4][4];
#pragma unroll
    for (int mt = 0; mt < 4; ++mt)
#pragma unroll
        for (int r = 0; r < 4; ++r) { af[mt][r] = accf[mt][r]; ab[mt][r] = accb[mt][r]; }
#pragma unroll
    for (int step = 1; step < 16; step <<= 1)
#pragma unroll
        for (int mt = 0; mt < 4; ++mt)
#pragma unroll
            for (int r = 0; r < 4; ++r) {
                af[mt][r] += __shfl_xor(af[mt][r], step);
                ab[mt][r] += __shfl_xor(ab[mt][r], step);
            }
    if (l15 == 0) {
#pragma unroll
        for (int mt = 0; mt < 4; ++mt)
#pragma unroll
            for (int r = 0; r < 4; ++r) {
                int m = mt * 16 + quad * 4 + r;
                red[wave * 128 + m] = af[mt][r];
                red[wave * 128 + DD + m] = ab[mt][r];
            }
    }
    __syncthreads();
    if (tid < 128) {
        float sum = red[tid] + red[128 + tid] + red[256 + tid] + red[384 + tid];
        red[tid] = sum;
    }
    __syncthreads();
    if (wave < 2) {
        const float* sv = red + wave * DD;
        int row0 = wave ? 129 : 65;
        float o = 0.f;
        for (int k = 0; k < DD; ++k) o += sv[k] * gWf[(row0 + k) * DD + lane];
        (wave ? qqb : ppb)[b * DD + lane] = o;
    }
}

// =============== K5: final selected pairs (MFMA) — 256 blocks x 128 threads (R14 verbatim) ===============
__global__ __launch_bounds__(128) void k_final(
        const void* __restrict__ emb,
        const int* __restrict__ pos, const unsigned short* __restrict__ hbf,
        const float* __restrict__ gWf, const unsigned int* __restrict__ eim,
        const float* __restrict__ ppb, const float* __restrict__ qqb,
        const float* __restrict__ linf, void* __restrict__ outv) {
    __shared__ __align__(16) unsigned short sgW[DD * SWP];
    const int b = blockIdx.x, tid = threadIdx.x;
    const int lane = tid & 63, wave = tid >> 6;
    const int l15 = lane & 15, quad = lane >> 4;
    const int fl = probe_fl(emb);

    {
        int m = tid >> 1;
        int k0 = (tid & 1) * 32;
        unsigned short tmp[32];
#pragma unroll
        for (int u = 0; u < 32; ++u) tmp[u] = f2bf_u(gWf[(k0 + u) * DD + m]);
#pragma unroll
        for (int q = 0; q < 4; ++q)
            *(short8*)(sgW + m * SWP + k0 + q * 8) = *(short8*)(tmp + q * 8);
    }

    int pp_ = b * 32 + wave * 16 + l15;
    int a = pos[2 * pp_], bb = pos[2 * pp_ + 1];
    short8 ha0 = *(const short8*)(hbf + a * DD + quad * 8);
    short8 hb0v = *(const short8*)(hbf + bb * DD + quad * 8);
    short8 ha1 = *(const short8*)(hbf + a * DD + 32 + quad * 8);
    short8 hb1v = *(const short8*)(hbf + bb * DD + 32 + quad * 8);
    short8 B0, B1;
#pragma unroll
    for (int j = 0; j < 8; ++j) {
        B0[j] = (short)f2bf_u(bfu2f((unsigned short)ha0[j]) * bfu2f((unsigned short)hb0v[j]));
        B1[j] = (short)f2bf_u(bfu2f((unsigned short)ha1[j]) * bfu2f((unsigned short)hb1v[j]));
    }
    __syncthreads();

    f32x4 C[4];
#pragma unroll
    for (int mt = 0; mt < 4; ++mt) C[mt] = (f32x4){0.f, 0.f, 0.f, 0.f};
#pragma unroll
    for (int mt = 0; mt < 4; ++mt) {
        short8 A0 = *(const short8*)(sgW + (mt * 16 + l15) * SWP + quad * 8);
        C[mt] = __builtin_amdgcn_mfma_f32_16x16x32_bf16(A0, B0, C[mt], 0, 0, 0);
    }
#pragma unroll
    for (int mt = 0; mt < 4; ++mt) {
        short8 A1 = *(const short8*)(sgW + (mt * 16 + l15) * SWP + 32 + quad * 8);
        C[mt] = __builtin_amdgcn_mfma_f32_16x16x32_bf16(A1, B1, C[mt], 0, 0, 0);
    }

    unsigned int iab = (unsigned int)(a * NN + bb), iba = (unsigned int)(bb * NN + a);
    float eab = (float)((eim[iab >> 5] >> (iab & 31)) & 1u);
    float eba = (float)((eim[iba >> 5] >> (iba & 31)) & 1u);

    float u1[4][4], u2[4][4];
    float s1 = 0.f, s12 = 0.f, s2 = 0.f, s22 = 0.f;
#pragma unroll
    for (int mt = 0; mt < 4; ++mt) {
        int m0 = mt * 16 + quad * 4;
        f32x4 w64v = *(const f32x4*)(gWf + 64 * DD + m0);
        f32x4 gbv  = *(const f32x4*)(gWf + 193 * DD + m0);
        f32x4 ppa  = *(const f32x4*)(ppb + a * DD + m0);
        f32x4 qqb_ = *(const f32x4*)(qqb + bb * DD + m0);
        f32x4 ppb_ = *(const f32x4*)(ppb + bb * DD + m0);
        f32x4 qqa  = *(const f32x4*)(qqb + a * DD + m0);
#pragma unroll
        for (int r = 0; r < 4; ++r) {
            float v1 = C[mt][r] + eab * w64v[r] + ppa[r] + qqb_[r] + gbv[r];
            float v2 = C[mt][r] + eba * w64v[r] + ppb_[r] + qqa[r] + gbv[r];
            u1[mt][r] = v1; u2[mt][r] = v2;
            s1 += v1; s12 += v1 * v1;
            s2 += v2; s22 += v2 * v2;
        }
    }
    s1 += __shfl_xor(s1, 16);  s1 += __shfl_xor(s1, 32);
    s12 += __shfl_xor(s12, 16); s12 += __shfl_xor(s12, 32);
    s2 += __shfl_xor(s2, 16);  s2 += __shfl_xor(s2, 32);
    s22 += __shfl_xor(s22, 16); s22 += __shfl_xor(s22, 32);
    float mean1 = s1 * (1.f / DD);
    float rs1 = rsqrtf(fmaxf(s12 * (1.f / DD) - mean1 * mean1, 0.f) + EPSF);
    float mrs1 = mean1 * rs1;
    float mean2 = s2 * (1.f / DD);
    float rs2 = rsqrtf(fmaxf(s22 * (1.f / DD) - mean2 * mean2, 0.f) + EPSF);
    float mrs2 = mean2 * rs2;

    float r = 0.f;
#pragma unroll
    for (int mt = 0; mt < 4; ++mt) {
        f32x4 lw = *(const f32x4*)(linf + mt * 16 + quad * 4);
#pragma unroll
        for (int rr = 0; rr < 4; ++rr) {
            float g1 = fmaxf(u1[mt][rr] * rs1 - mrs1, 0.f);
            float g2 = fmaxf(u2[mt][rr] * rs2 - mrs2, 0.f);
            r += g1 * g2 * lw[rr];
        }
    }
    r += __shfl_xor(r, 16); r += __shfl_xor(r, 32);
    if (quad == 0) {
        float res = r + linf[DD];
        if (fl) ((float*)outv)[pp_] = res;
        else    ((bf16*)outv)[pp_] = __float2bfloat16(res);
    }
}

extern "C" void kernel_launch(void* const* d_in, const int* in_sizes, int n_in,
                              void* d_out, int out_size, void* d_ws, size_t ws_size,
                              hipStream_t stream) {
    const int* x   = (const int*)d_in[0];
    const int* ei  = (const int*)d_in[1];
    const int* pos = (const int*)d_in[2];
    const void* emb = d_in[3];

    char* w = (char*)d_ws;
    auto alloc = [&](size_t bytes) {
        void* q = (void*)w;
        w += (bytes + 255) & ~(size_t)255;
        return q;
    };
    unsigned int* eim  = (unsigned int*)alloc(NN * NN / 8);
    unsigned int* eimT = (unsigned int*)alloc(NN * NN / 8);
    float* h0   = (float*)alloc(NN * DD * 4);
    float* h1   = (float*)alloc(NN * DD * 4);
    float* h2   = (float*)alloc(NN * DD * 4);
    unsigned short* hbf = (unsigned short*)alloc(NN * DD * 2 + 8192);  // +8K: last-iter prefetch over-read
    float* Wlf  = (float*)alloc(2 * DD * DD * 4);
    float* blf  = (float*)alloc(2 * DD * 4);
    float* Wrf  = (float*)alloc(2 * DD * DD * 4);
    float* WfT  = (float*)alloc(DD * DD * 4);
    float* hbw  = (float*)alloc(128 * 4);
    float* gWf  = (float*)alloc(194 * DD * 4);
    float* linf = (float*)alloc(65 * 4);
    float* ppb  = (float*)alloc(NN * DD * 4);
    float* qqb  = (float*)alloc(NN * DD * 4);
    int* rowptr = (int*)alloc((NN + 1) * 4);
    int* csrc   = (int*)alloc(EE * 4);

    k_prep<<<98, 1024, 0, stream>>>(emb, d_in[4], d_in[5], d_in[6], d_in[7], d_in[8],
                                    d_in[9], d_in[10], d_in[11], d_in[12],
                                    x, ei, Wlf, blf, Wrf, WfT, hbw, gWf, linf,
                                    h0, eim, eimT, rowptr, csrc);
    k_sage0<<<256, 256, 0, stream>>>(emb, ei, rowptr, csrc, h0, Wlf, d_in[5], Wrf,
                                     h1, eim, eimT);
    k_sage1<<<256, 256, 0, stream>>>(emb, rowptr, csrc, h1, Wlf, d_in[5], Wrf, h2, hbf);
    k_bstage<<<NN, 256, 0, stream>>>(h2, hbf, WfT, hbw, eim, eimT, gWf, ppb, qqb);
    k_final<<<PP / 32, 128, 0, stream>>>(emb, pos, hbf, gWf, eim, ppb, qqb, linf, d_out);
}

// Round 16
// 145.831 us; speedup vs baseline: 1.1937x; 1.0067x over previous
//
#include <hip/hip_runtime.h>
#include <hip/hip_bf16.h>

#define NN 1024
#define DD 64
#define EE 16384
#define PP 8192
#define EPSF 1e-5f
#define SWP (DD + 8)   // padded LDS row stride in shorts (144 B)

typedef __hip_bfloat16 bf16;
typedef __attribute__((ext_vector_type(8))) short short8;
typedef __attribute__((ext_vector_type(4))) float f32x4;

static __device__ __forceinline__ float dec1(const void* src, int i, int fl) {
    if (fl) return ((const float*)src)[i];
    return __bfloat162float(((const bf16*)src)[i]);
}
static __device__ __forceinline__ unsigned short f2bf_u(float f) {
    bf16 h = __float2bfloat16(f);
    return *reinterpret_cast<unsigned short*>(&h);
}
static __device__ __forceinline__ float bfu2f(unsigned short u) {
    return __uint_as_float(((unsigned int)u) << 16);
}
static __device__ __forceinline__ int probe_fl(const void* emb) {
    int lane = threadIdx.x & 63;
    unsigned short raw = ((const unsigned short*)emb)[lane];
    float v = __uint_as_float(((unsigned int)raw) << 16);
    return (__ballot(!(fabsf(v) <= 1e3f)) != 0ull) ? 1 : 0;
}

// =============== K1: decode + embed + zero bitmaps + fat-block CSR ===============
__global__ __launch_bounds__(1024) void k_prep(
        const void* __restrict__ emb, const void* __restrict__ sWl,
        const void* __restrict__ sbl, const void* __restrict__ sWr,
        const void* __restrict__ hW, const void* __restrict__ hb,
        const void* __restrict__ gW, const void* __restrict__ gb,
        const void* __restrict__ lW, const void* __restrict__ lb,
        const int* __restrict__ x, const int* __restrict__ ei,
        float* __restrict__ Wlf, float* __restrict__ blf, float* __restrict__ Wrf,
        float* __restrict__ WfT, float* __restrict__ hbw,
        float* __restrict__ gWf, float* __restrict__ linf,
        unsigned short* __restrict__ gWbfT,
        float* __restrict__ h0,
        unsigned int* __restrict__ eim, unsigned int* __restrict__ eimT,
        int* __restrict__ rowptr, int* __restrict__ csrc) {
    __shared__ int sdeg[NN];
    __shared__ int stmp[1024];
    const int b = blockIdx.x, tid = threadIdx.x;
    const int fl = probe_fl(emb);

    if (b < 97) {
        const int vb = b * 4 + (tid >> 8);
        const int vt = tid & 255;
        if (vb < 256) {
            int z = vb * 256 + vt;
            if (z < 32768) eim[z] = 0u;
            else           eimT[z - 32768] = 0u;
        }
        if (vb < 32) { int i = vb * 256 + vt; Wlf[i] = dec1(sWl, i, fl); }
        else if (vb == 32) { if (vt < 128) blf[vt] = dec1(sbl, vt, fl); }
        else if (vb < 65) { int i = (vb - 33) * 256 + vt; Wrf[i] = dec1(sWr, i, fl); }
        else if (vb < 82) {
            int i = (vb - 65) * 256 + vt;
            if (i < 4096) { int n = i >> 6, k = i & 63; WfT[n * DD + k] = dec1(hW, k * DD + n, fl); }
            else if (i < 4160) hbw[i - 4096] = dec1(hb, i - 4096, fl);
            else if (i < 4224) hbw[64 + (i - 4160)] = dec1(hW, 64 * DD + (i - 4160), fl);
        } else if (vb < 131) {
            int i = (vb - 82) * 256 + vt;
            if (i < 193 * DD) gWf[i] = dec1(gW, i, fl);
            else if (i < 194 * DD) gWf[i] = dec1(gb, i - 193 * DD, fl);
        } else if (vb == 131) {
            if (vt < DD) linf[vt] = dec1(lW, vt, fl);
            else if (vt == DD) linf[DD] = dec1(lb, 0, fl);
            // gW -> bf16 transposed [m][k] for k_final A-frags (direct from input; no race)
#pragma unroll
            for (int u = 0; u < 16; ++u) {
                int i = vt * 16 + u;
                int m = i >> 6, k = i & 63;
                gWbfT[i] = f2bf_u(dec1(gW, k * DD + m, fl));
            }
        } else if (vb < 388) {
            int i = (vb - 132) * 256 + vt;
            int node = i >> 6, f = i & 63;
            h0[i] = dec1(emb, x[node] * DD + f, fl);
        }
    } else {
        sdeg[tid] = 0;
        __syncthreads();
        for (int base = 0; base < EE; base += 8192) {
            int d8[8];
#pragma unroll
            for (int u = 0; u < 8; ++u) d8[u] = ei[EE + base + u * 1024 + tid];
#pragma unroll
            for (int u = 0; u < 8; ++u) atomicAdd(&sdeg[d8[u]], 1);
        }
        __syncthreads();
        int v = sdeg[tid];
        stmp[tid] = v;
        __syncthreads();
        for (int off = 1; off < 1024; off <<= 1) {
            int a = (tid >= off) ? stmp[tid - off] : 0;
            __syncthreads();
            stmp[tid] += a;
            __syncthreads();
        }
        int excl = stmp[tid] - v;
        rowptr[tid] = excl;
        sdeg[tid] = excl;
        if (tid == 1023) rowptr[NN] = stmp[1023];
        __syncthreads();
        for (int base = 0; base < EE; base += 8192) {
            int d8[8], s8[8];
#pragma unroll
            for (int u = 0; u < 8; ++u) {
                d8[u] = ei[EE + base + u * 1024 + tid];
                s8[u] = ei[base + u * 1024 + tid];
            }
#pragma unroll
            for (int u = 0; u < 8; ++u) {
                int c = atomicAdd(&sdeg[d8[u]], 1);
                csrc[c] = s8[u];
            }
        }
    }
}

// =============== SAGE body with LDS-staged weights (R14 verbatim) ===============
static __device__ __forceinline__ void sage_core(
        const float* sWl, const float* sWr, float* sa, float* sh,
        int node, int lane,
        const int* __restrict__ rowptr, const int* __restrict__ csrc,
        const float* __restrict__ hin, const void* __restrict__ sbl, int boff, int fl,
        float* __restrict__ hout, unsigned short* __restrict__ hbf) {
    int r0 = rowptr[node], r1 = rowptr[node + 1];
    float s = 0.f;
    int r = r0;
    for (; r + 4 <= r1; r += 4) {
        int i0 = csrc[r], i1 = csrc[r + 1], i2 = csrc[r + 2], i3 = csrc[r + 3];
        float v0 = hin[i0 * DD + lane], v1 = hin[i1 * DD + lane];
        float v2 = hin[i2 * DD + lane], v3 = hin[i3 * DD + lane];
        s += (v0 + v1) + (v2 + v3);
    }
    for (; r < r1; ++r) s += hin[csrc[r] * DD + lane];
    sa[lane] = s / (float)max(r1 - r0, 1);
    sh[lane] = hin[node * DD + lane];
    float o = dec1(sbl, boff + lane, fl);
    for (int k = 0; k < DD; ++k)
        o += sa[k] * sWl[k * DD + lane] + sh[k] * sWr[k * DD + lane];
    float m = o;
    for (int off = 32; off; off >>= 1) m += __shfl_xor(m, off);
    m *= (1.f / DD);
    float d0 = o - m;
    float v = d0 * d0;
    for (int off = 32; off; off >>= 1) v += __shfl_xor(v, off);
    v *= (1.f / DD);
    float rr = d0 * rsqrtf(v + EPSF);
    hout[node * DD + lane] = rr;
    if (hbf) hbf[node * DD + lane] = f2bf_u(rr);
}

// =============== K2: SAGE round 0 + edge-bitmap atomics ===============
__global__ __launch_bounds__(256) void k_sage0(
        const void* __restrict__ emb, const int* __restrict__ ei,
        const int* __restrict__ rowptr, const int* __restrict__ csrc,
        const float* __restrict__ h0,
        const float* __restrict__ Wlf, const void* __restrict__ sbl,
        const float* __restrict__ Wrf,
        float* __restrict__ h1,
        unsigned int* __restrict__ eim, unsigned int* __restrict__ eimT) {
    __shared__ __align__(16) float sWl[DD * DD];
    __shared__ __align__(16) float sWr[DD * DD];
    __shared__ float sa4[4 * DD], sh4[4 * DD];
    const int b = blockIdx.x, tid = threadIdx.x;
    const int lane = tid & 63, wave = tid >> 6;
    const int fl = probe_fl(emb);
    for (int i = tid * 4; i < DD * DD; i += 1024) {
        *(float4*)(sWl + i) = *(const float4*)(Wlf + i);
        *(float4*)(sWr + i) = *(const float4*)(Wrf + i);
    }
    if (tid < 64) {
        int e = b * 64 + tid;
        int s = ei[e], d = ei[EE + e];
        unsigned int idx = (unsigned int)(s * NN + d);
        atomicOr(&eim[idx >> 5], 1u << (idx & 31));
        unsigned int idxT = (unsigned int)(d * NN + s);
        atomicOr(&eimT[idxT >> 5], 1u << (idxT & 31));
    }
    __syncthreads();
    sage_core(sWl, sWr, sa4 + wave * DD, sh4 + wave * DD, b * 4 + wave, lane,
              rowptr, csrc, h0, sbl, 0, fl, h1, (unsigned short*)nullptr);
}

// =============== K3: SAGE round 1 ===============
__global__ __launch_bounds__(256) void k_sage1(
        const void* __restrict__ emb,
        const int* __restrict__ rowptr, const int* __restrict__ csrc,
        const float* __restrict__ h1,
        const float* __restrict__ Wlf, const void* __restrict__ sbl,
        const float* __restrict__ Wrf,
        float* __restrict__ h2, unsigned short* __restrict__ hbf) {
    __shared__ __align__(16) float sWl[DD * DD];
    __shared__ __align__(16) float sWr[DD * DD];
    __shared__ float sa4[4 * DD], sh4[4 * DD];
    const int b = blockIdx.x, tid = threadIdx.x;
    const int lane = tid & 63, wave = tid >> 6;
    const int fl = probe_fl(emb);
    for (int i = tid * 4; i < DD * DD; i += 1024) {
        *(float4*)(sWl + i) = *(const float4*)(Wlf + DD * DD + i);
        *(float4*)(sWr + i) = *(const float4*)(Wrf + DD * DD + i);
    }
    __syncthreads();
    sage_core(sWl, sWr, sa4 + wave * DD, sh4 + wave * DD, b * 4 + wave, lane,
              rowptr, csrc, h1, sbl, DD, fl, h2, hbf);
}

// =============== K4: B-stage — R15 epilogue + eim/eimT software pipelining ===============
// NOTE: plain __launch_bounds__(256) — (256,4) capped VGPR at 64 and spilled (R8).
__global__ __launch_bounds__(256) void k_bstage(
        const float* __restrict__ h2, const unsigned short* __restrict__ hbf,
        const float* __restrict__ WfT, const float* __restrict__ hbw,
        const unsigned int* __restrict__ eim, const unsigned int* __restrict__ eimT,
        const float* __restrict__ gWf,
        float* __restrict__ ppb, float* __restrict__ qqb) {
    __shared__ __align__(16) unsigned short sW[DD * SWP];  // 9216 B
    __shared__ __align__(16) float red[4 * 128];           // 2048 B
    __shared__ float swc[2];                               // {sum w64, sum w64^2}
    const int b = blockIdx.x, tid = threadIdx.x;
    const int lane = tid & 63, wave = tid >> 6;
    const int l15 = lane & 15, quad = lane >> 4;

    {
        int m = tid >> 2;
        int k0 = (tid & 3) * 16;
        const float* hi = h2 + b * DD;
        const float* wr = WfT + m * DD;
        unsigned short tmp[16];
#pragma unroll
        for (int u = 0; u < 16; ++u) tmp[u] = f2bf_u(hi[k0 + u] * wr[k0 + u]);
        *(short8*)(sW + m * SWP + k0) = *(short8*)tmp;
        *(short8*)(sW + m * SWP + k0 + 8) = *(short8*)(tmp + 8);
    }
    if (wave == 0) {
        float wv = hbw[64 + lane];
        float s = wv, s2 = wv * wv;
        for (int off = 32; off; off >>= 1) {
            s += __shfl_xor(s, off);
            s2 += __shfl_xor(s2, off);
        }
        if (lane == 0) { swc[0] = s; swc[1] = s2; }
    }
    __syncthreads();
    const float SW = swc[0], SWW = swc[1];

    short8 Af[4][2];
#pragma unroll
    for (int mt = 0; mt < 4; ++mt)
#pragma unroll
        for (int kt = 0; kt < 2; ++kt)
            Af[mt][kt] = *(const short8*)(sW + (mt * 16 + l15) * SWP + kt * 32 + quad * 8);

    f32x4 hb04[4], hww4[4];
#pragma unroll
    for (int mt = 0; mt < 4; ++mt) {
        hb04[mt] = *(const f32x4*)(hbw + mt * 16 + quad * 4);
        hww4[mt] = *(const f32x4*)(hbw + 64 + mt * 16 + quad * 4);
    }

    f32x4 accf[4], accb[4];
#pragma unroll
    for (int mt = 0; mt < 4; ++mt) {
        accf[mt] = (f32x4){0.f, 0.f, 0.f, 0.f};
        accb[mt] = (f32x4){0.f, 0.f, 0.f, 0.f};
    }

    const unsigned short* pB = hbf + (wave * 16 + l15) * DD + quad * 8;
    const unsigned int* pF = eim + b * 32 + (wave >> 1);
    const unsigned int* pBk = eimT + b * 32 + (wave >> 1);
    const int shft = (wave & 1) * 16;

    short8 B0 = *(const short8*)(pB);
    short8 B1 = *(const short8*)(pB + 32);
    pB += 4096;
    unsigned int wfC = pF[0], wbC = pBk[0];   // pipelined bitmap words
    pF += 2; pBk += 2;

    for (int it = 0; it < 16; ++it) {
        short8 cB0 = B0, cB1 = B1;
        B0 = *(const short8*)(pB);        // last-iter prefetch reads unused ws bytes (safe)
        B1 = *(const short8*)(pB + 32);
        pB += 4096;
        unsigned int sf = (wfC >> shft) & 0xFFFFu;
        unsigned int sb = (wbC >> shft) & 0xFFFFu;
        wfC = pF[0]; wbC = pBk[0];        // prefetch next (over-read safe in ws)
        pF += 2; pBk += 2;

        f32x4 C[4];
#pragma unroll
        for (int mt = 0; mt < 4; ++mt) C[mt] = hb04[mt];
#pragma unroll
        for (int mt = 0; mt < 4; ++mt)
            C[mt] = __builtin_amdgcn_mfma_f32_16x16x32_bf16(Af[mt][0], cB0, C[mt], 0, 0, 0);
#pragma unroll
        for (int mt = 0; mt < 4; ++mt)
            C[mt] = __builtin_amdgcn_mfma_f32_16x16x32_bf16(Af[mt][1], cB1, C[mt], 0, 0, 0);

        float ef = (float)((sf >> l15) & 1u);
        f32x4 efv = {ef, ef, ef, ef};
        f32x4 s1a = {0.f, 0.f, 0.f, 0.f}, s2a = {0.f, 0.f, 0.f, 0.f};
#pragma unroll
        for (int mt = 0; mt < 4; ++mt) {
            C[mt] += efv * hww4[mt];
            s1a += C[mt];
            s2a += C[mt] * C[mt];
        }
        float s1 = (s1a.x + s1a.y) + (s1a.z + s1a.w);
        float s2 = (s2a.x + s2a.y) + (s2a.z + s2a.w);
        s1 += __shfl_xor(s1, 16); s1 += __shfl_xor(s1, 32);
        s2 += __shfl_xor(s2, 16); s2 += __shfl_xor(s2, 32);
        float mean = s1 * (1.f / DD);
        float var = fmaxf(s2 * (1.f / DD) - mean * mean, 0.f);
        float rs = rsqrtf(var + EPSF);
        float mrs = mean * rs;
        f32x4 rsv = {rs, rs, rs, rs}, mrsv = {mrs, mrs, mrs, mrs};
        f32x4 zero = {0.f, 0.f, 0.f, 0.f};

        if (sf == sb) {
#pragma unroll
            for (int mt = 0; mt < 4; ++mt) {
                f32x4 u = __builtin_elementwise_max(C[mt] * rsv - mrsv, zero);
                accf[mt] += u;
                accb[mt] += u;
            }
        } else {
#pragma unroll
            for (int mt = 0; mt < 4; ++mt)
                accf[mt] += __builtin_elementwise_max(C[mt] * rsv - mrsv, zero);
            float de = (float)((sb >> l15) & 1u) - ef;
            f32x4 dva = {0.f, 0.f, 0.f, 0.f};
#pragma unroll
            for (int mt = 0; mt < 4; ++mt) dva += C[mt] * hww4[mt];
            float dot = (dva.x + dva.y) + (dva.z + dva.w);
            dot += __shfl_xor(dot, 16); dot += __shfl_xor(dot, 32);
            float t1 = s1 + de * SW;
            float t2 = s2 + 2.f * de * dot + de * de * SWW;
            float mean2 = t1 * (1.f / DD);
            float var2 = fmaxf(t2 * (1.f / DD) - mean2 * mean2, 0.f);
            float rs2 = rsqrtf(var2 + EPSF);
            float mrs2 = mean2 * rs2;
            float drs = de * rs2;
            f32x4 rs2v = {rs2, rs2, rs2, rs2};
            f32x4 mrs2v = {mrs2, mrs2, mrs2, mrs2};
            f32x4 drsv = {drs, drs, drs, drs};
#pragma unroll
            for (int mt = 0; mt < 4; ++mt) {
                f32x4 th = mrs2v - drsv * hww4[mt];
                accb[mt] += __builtin_elementwise_max(C[mt] * rs2v - th, zero);
            }
        }
    }

    float af[4][4], ab[4][4];
#pragma unroll
    for (int mt = 0; mt < 4; ++mt)
#pragma unroll
        for (int r = 0; r < 4; ++r) { af[mt][r] = accf[mt][r]; ab[mt][r] = accb[mt][r]; }
#pragma unroll
    for (int step = 1; step < 16; step <<= 1)
#pragma unroll
        for (int mt = 0; mt < 4; ++mt)
#pragma unroll
            for (int r = 0; r < 4; ++r) {
                af[mt][r] += __shfl_xor(af[mt][r], step);
                ab[mt][r] += __shfl_xor(ab[mt][r], step);
            }
    if (l15 == 0) {
#pragma unroll
        for (int mt = 0; mt < 4; ++mt)
#pragma unroll
            for (int r = 0; r < 4; ++r) {
                int m = mt * 16 + quad * 4 + r;
                red[wave * 128 + m] = af[mt][r];
                red[wave * 128 + DD + m] = ab[mt][r];
            }
    }
    __syncthreads();
    if (tid < 128) {
        float sum = red[tid] + red[128 + tid] + red[256 + tid] + red[384 + tid];
        red[tid] = sum;
    }
    __syncthreads();
    if (wave < 2) {
        const float* sv = red + wave * DD;
        int row0 = wave ? 129 : 65;
        float o = 0.f;
        for (int k = 0; k < DD; ++k) o += sv[k] * gWf[(row0 + k) * DD + lane];
        (wave ? qqb : ppb)[b * DD + lane] = o;
    }
}

// =============== K5: final selected pairs — A-frags direct from precomputed gWbfT ===============
__global__ __launch_bounds__(128) void k_final(
        const void* __restrict__ emb,
        const int* __restrict__ pos, const unsigned short* __restrict__ hbf,
        const float* __restrict__ gWf, const unsigned short* __restrict__ gWbfT,
        const unsigned int* __restrict__ eim,
        const float* __restrict__ ppb, const float* __restrict__ qqb,
        const float* __restrict__ linf, void* __restrict__ outv) {
    const int b = blockIdx.x, tid = threadIdx.x;
    const int lane = tid & 63, wave = tid >> 6;
    const int l15 = lane & 15, quad = lane >> 4;
    const int fl = probe_fl(emb);

    // A-frags from global (block-invariant, L1/L2-resident 8KB)
    short8 A0f[4], A1f[4];
#pragma unroll
    for (int mt = 0; mt < 4; ++mt) {
        A0f[mt] = *(const short8*)(gWbfT + (mt * 16 + l15) * DD + quad * 8);
        A1f[mt] = *(const short8*)(gWbfT + (mt * 16 + l15) * DD + 32 + quad * 8);
    }

    int pp_ = b * 32 + wave * 16 + l15;
    int a = pos[2 * pp_], bb = pos[2 * pp_ + 1];
    short8 ha0 = *(const short8*)(hbf + a * DD + quad * 8);
    short8 hb0v = *(const short8*)(hbf + bb * DD + quad * 8);
    short8 ha1 = *(const short8*)(hbf + a * DD + 32 + quad * 8);
    short8 hb1v = *(const short8*)(hbf + bb * DD + 32 + quad * 8);
    short8 B0, B1;
#pragma unroll
    for (int j = 0; j < 8; ++j) {
        B0[j] = (short)f2bf_u(bfu2f((unsigned short)ha0[j]) * bfu2f((unsigned short)hb0v[j]));
        B1[j] = (short)f2bf_u(bfu2f((unsigned short)ha1[j]) * bfu2f((unsigned short)hb1v[j]));
    }

    f32x4 C[4];
#pragma unroll
    for (int mt = 0; mt < 4; ++mt) C[mt] = (f32x4){0.f, 0.f, 0.f, 0.f};
#pragma unroll
    for (int mt = 0; mt < 4; ++mt)
        C[mt] = __builtin_amdgcn_mfma_f32_16x16x32_bf16(A0f[mt], B0, C[mt], 0, 0, 0);
#pragma unroll
    for (int mt = 0; mt < 4; ++mt)
        C[mt] = __builtin_amdgcn_mfma_f32_16x16x32_bf16(A1f[mt], B1, C[mt], 0, 0, 0);

    unsigned int iab = (unsigned int)(a * NN + bb), iba = (unsigned int)(bb * NN + a);
    float eab = (float)((eim[iab >> 5] >> (iab & 31)) & 1u);
    float eba = (float)((eim[iba >> 5] >> (iba & 31)) & 1u);

    float u1[4][4], u2[4][4];
    float s1 = 0.f, s12 = 0.f, s2 = 0.f, s22 = 0.f;
#pragma unroll
    for (int mt = 0; mt < 4; ++mt) {
        int m0 = mt * 16 + quad * 4;
        f32x4 w64v = *(const f32x4*)(gWf + 64 * DD + m0);
        f32x4 gbv  = *(const f32x4*)(gWf + 193 * DD + m0);
        f32x4 ppa  = *(const f32x4*)(ppb + a * DD + m0);
        f32x4 qqb_ = *(const f32x4*)(qqb + bb * DD + m0);
        f32x4 ppb_ = *(const f32x4*)(ppb + bb * DD + m0);
        f32x4 qqa  = *(const f32x4*)(qqb + a * DD + m0);
#pragma unroll
        for (int r = 0; r < 4; ++r) {
            float v1 = C[mt][r] + eab * w64v[r] + ppa[r] + qqb_[r] + gbv[r];
            float v2 = C[mt][r] + eba * w64v[r] + ppb_[r] + qqa[r] + gbv[r];
            u1[mt][r] = v1; u2[mt][r] = v2;
            s1 += v1; s12 += v1 * v1;
            s2 += v2; s22 += v2 * v2;
        }
    }
    s1 += __shfl_xor(s1, 16);  s1 += __shfl_xor(s1, 32);
    s12 += __shfl_xor(s12, 16); s12 += __shfl_xor(s12, 32);
    s2 += __shfl_xor(s2, 16);  s2 += __shfl_xor(s2, 32);
    s22 += __shfl_xor(s22, 16); s22 += __shfl_xor(s22, 32);
    float mean1 = s1 * (1.f / DD);
    float rs1 = rsqrtf(fmaxf(s12 * (1.f / DD) - mean1 * mean1, 0.f) + EPSF);
    float mrs1 = mean1 * rs1;
    float mean2 = s2 * (1.f / DD);
    float rs2 = rsqrtf(fmaxf(s22 * (1.f / DD) - mean2 * mean2, 0.f) + EPSF);
    float mrs2 = mean2 * rs2;

    float r = 0.f;
#pragma unroll
    for (int mt = 0; mt < 4; ++mt) {
        f32x4 lw = *(const f32x4*)(linf + mt * 16 + quad * 4);
#pragma unroll
        for (int rr = 0; rr < 4; ++rr) {
            float g1 = fmaxf(u1[mt][rr] * rs1 - mrs1, 0.f);
            float g2 = fmaxf(u2[mt][rr] * rs2 - mrs2, 0.f);
            r += g1 * g2 * lw[rr];
        }
    }
    r += __shfl_xor(r, 16); r += __shfl_xor(r, 32);
    if (quad == 0) {
        float res = r + linf[DD];
        if (fl) ((float*)outv)[pp_] = res;
        else    ((bf16*)outv)[pp_] = __float2bfloat16(res);
    }
}

extern "C" void kernel_launch(void* const* d_in, const int* in_sizes, int n_in,
                              void* d_out, int out_size, void* d_ws, size_t ws_size,
                              hipStream_t stream) {
    const int* x   = (const int*)d_in[0];
    const int* ei  = (const int*)d_in[1];
    const int* pos = (const int*)d_in[2];
    const void* emb = d_in[3];

    char* w = (char*)d_ws;
    auto alloc = [&](size_t bytes) {
        void* q = (void*)w;
        w += (bytes + 255) & ~(size_t)255;
        return q;
    };
    unsigned int* eim  = (unsigned int*)alloc(NN * NN / 8);
    unsigned int* eimT = (unsigned int*)alloc(NN * NN / 8);
    float* h0   = (float*)alloc(NN * DD * 4);
    float* h1   = (float*)alloc(NN * DD * 4);
    float* h2   = (float*)alloc(NN * DD * 4);
    unsigned short* hbf = (unsigned short*)alloc(NN * DD * 2 + 8192);  // +8K: last-iter prefetch over-read
    float* Wlf  = (float*)alloc(2 * DD * DD * 4);
    float* blf  = (float*)alloc(2 * DD * 4);
    float* Wrf  = (float*)alloc(2 * DD * DD * 4);
    float* WfT  = (float*)alloc(DD * DD * 4);
    float* hbw  = (float*)alloc(128 * 4);
    float* gWf  = (float*)alloc(194 * DD * 4);
    float* linf = (float*)alloc(65 * 4);
    unsigned short* gWbfT = (unsigned short*)alloc(DD * DD * 2);
    float* ppb  = (float*)alloc(NN * DD * 4);
    float* qqb  = (float*)alloc(NN * DD * 4);
    int* rowptr = (int*)alloc((NN + 1) * 4);
    int* csrc   = (int*)alloc(EE * 4);

    k_prep<<<98, 1024, 0, stream>>>(emb, d_in[4], d_in[5], d_in[6], d_in[7], d_in[8],
                                    d_in[9], d_in[10], d_in[11], d_in[12],
                                    x, ei, Wlf, blf, Wrf, WfT, hbw, gWf, linf, gWbfT,
                                    h0, eim, eimT, rowptr, csrc);
    k_sage0<<<256, 256, 0, stream>>>(emb, ei, rowptr, csrc, h0, Wlf, d_in[5], Wrf,
                                     h1, eim, eimT);
    k_sage1<<<256, 256, 0, stream>>>(emb, rowptr, csrc, h1, Wlf, d_in[5], Wrf, h2, hbf);
    k_bstage<<<NN, 256, 0, stream>>>(h2, hbf, WfT, hbw, eim, eimT, gWf, ppb, qqb);
    k_final<<<PP / 32, 128, 0, stream>>>(emb, pos, hbf, gWf, gWbfT, eim, ppb, qqb, linf, d_out);
}